// Round 1
// baseline (10805.815 us; speedup 1.0000x reference)
//
#include <hip/hip_runtime.h>
#include <cstddef>

#define TPB 256

// ---------------------------------------------------------------------------
// Generic grouped conv (NCHW). w: (Cout, Cin/groups, K, K). N=8 via blockIdx.z.
// flags: bit0 = accumulate into out, bit1 = relu on output.
// ---------------------------------------------------------------------------
template<int K, bool RELU_IN>
__global__ void conv2d_kernel(const float* __restrict__ in, const float* __restrict__ w,
                              const float* __restrict__ bias, float* __restrict__ out,
                              int Cin, int Hin, int Win, int Cout, int Hout, int Wout,
                              int stride, int pad, int groups, int flags)
{
    __shared__ float sw[1152];           // max icg*K*K = 128*9
    const int n  = blockIdx.z;
    const int oc = blockIdx.y;
    const int icg = Cin / groups;
    const int g = oc / (Cout / groups);
    const int wsz = icg * K * K;
    for (int i = threadIdx.x; i < wsz; i += blockDim.x)
        sw[i] = w[(size_t)oc * wsz + i];
    __syncthreads();

    const int p = blockIdx.x * blockDim.x + threadIdx.x;
    if (p >= Hout * Wout) return;
    const int oy = p / Wout, ox = p - oy * Wout;

    float acc = bias ? bias[oc] : 0.0f;
    const float* inb = in + ((size_t)n * Cin + (size_t)g * icg) * Hin * Win;
    for (int ic = 0; ic < icg; ++ic) {
        const float* inc = inb + (size_t)ic * Hin * Win;
        const float* swc = sw + ic * K * K;
        #pragma unroll
        for (int ky = 0; ky < K; ++ky) {
            const int iy = oy * stride - pad + ky;
            if (iy < 0 || iy >= Hin) continue;
            #pragma unroll
            for (int kx = 0; kx < K; ++kx) {
                const int ix = ox * stride - pad + kx;
                if (ix < 0 || ix >= Win) continue;
                float v = inc[(size_t)iy * Win + ix];
                if (RELU_IN) v = fmaxf(v, 0.0f);
                acc = fmaf(v, swc[ky * K + kx], acc);
            }
        }
    }
    const size_t oidx = ((size_t)n * Cout + oc) * Hout * Wout + p;
    if (flags & 1) acc += out[oidx];
    if (flags & 2) acc = fmaxf(acc, 0.0f);
    out[oidx] = acc;
}

// ---------------------------------------------------------------------------
// Grouped ConvTranspose2d, torch layout w: (Cin, Cout/groups, K, K). K=4, s=2.
// flags: bit1 = relu on output.
// ---------------------------------------------------------------------------
template<int K>
__global__ void convt2d_kernel(const float* __restrict__ in, const float* __restrict__ w,
                               const float* __restrict__ bias, float* __restrict__ out,
                               int Cin, int Hin, int Win, int Cout, int Hout, int Wout,
                               int stride, int pad, int groups, int flags)
{
    __shared__ float sw[1024];           // max icg*K*K = 64*16
    const int n = blockIdx.z, oc = blockIdx.y;
    const int icg = Cin / groups, ocg = Cout / groups;
    const int g = oc / ocg, of = oc - g * ocg;
    const int wsz = icg * K * K;
    for (int i = threadIdx.x; i < wsz; i += blockDim.x) {
        const int ic = i / (K * K), t = i - ic * (K * K);
        sw[i] = w[((size_t)(g * icg + ic) * ocg + of) * (K * K) + t];
    }
    __syncthreads();

    const int p = blockIdx.x * blockDim.x + threadIdx.x;
    if (p >= Hout * Wout) return;
    const int oy = p / Wout, ox = p - oy * Wout;

    float acc = bias ? bias[oc] : 0.0f;
    const float* inb = in + ((size_t)n * Cin + (size_t)g * icg) * Hin * Win;
    #pragma unroll
    for (int ky = 0; ky < K; ++ky) {
        const int ty = oy + pad - ky;
        if (ty % stride) continue;           // negative ty gives nonzero remainder -> skip
        const int iy = ty / stride;
        if (iy < 0 || iy >= Hin) continue;
        #pragma unroll
        for (int kx = 0; kx < K; ++kx) {
            const int tx = ox + pad - kx;
            if (tx % stride) continue;
            const int ix = tx / stride;
            if (ix < 0 || ix >= Win) continue;
            const float* ip = inb + (size_t)iy * Win + ix;
            const float* wp = sw + ky * K + kx;
            float s = 0.0f;
            for (int ic = 0; ic < icg; ++ic)
                s = fmaf(ip[(size_t)ic * Hin * Win], wp[ic * K * K], s);
            acc += s;
        }
    }
    const size_t oidx = ((size_t)n * Cout + oc) * Hout * Wout + p;
    if (flags & 2) acc = fmaxf(acc, 0.0f);
    out[oidx] = acc;
}

// ---------------------------------------------------------------------------
// Fused encoder head: relu(concat(1x1(x[:, :1], dw), 1x1(x[:, 1:], rw)))
// x: (8,4,256,256) -> out: (8,64,256,256)
// ---------------------------------------------------------------------------
__global__ void head_kernel(const float* __restrict__ x,
                            const float* __restrict__ dw, const float* __restrict__ db,
                            const float* __restrict__ rw, const float* __restrict__ rb,
                            float* __restrict__ out)
{
    const long long idx = (long long)blockIdx.x * TPB + threadIdx.x;
    const int HW = 256 * 256;
    if (idx >= 8LL * 64 * HW) return;
    const int p = (int)(idx % HW);
    const int t = (int)(idx / HW);
    const int c = t & 63, n = t >> 6;
    const float* xb = x + (size_t)n * 4 * HW;
    float v;
    if (c < 32) {
        v = fmaf(xb[p], dw[c], db[c]);
    } else {
        const int cc = c - 32;
        v = rb[cc];
        v = fmaf(xb[(size_t)HW + p],     rw[cc * 3 + 0], v);
        v = fmaf(xb[(size_t)2 * HW + p], rw[cc * 3 + 1], v);
        v = fmaf(xb[(size_t)3 * HW + p], rw[cc * 3 + 2], v);
    }
    out[idx] = fmaxf(v, 0.0f);
}

// ---------------------------------------------------------------------------
// Channel regroup: out(8,256,HW) = cat(a[:64], b[:64], a[64:], b[64:]) per n.
// ---------------------------------------------------------------------------
__global__ void regroup_kernel(const float* __restrict__ a, const float* __restrict__ b,
                               float* __restrict__ out, int HW)
{
    const long long idx = (long long)blockIdx.x * TPB + threadIdx.x;
    const long long total = 8LL * 256 * HW;
    if (idx >= total) return;
    const int p = (int)(idx % HW);
    const int t = (int)(idx / HW);
    const int c = t & 255, n = t >> 8;
    const int q = c >> 6, r = c & 63;
    const float* src = (q & 1) ? b : a;
    const int ch = (q >> 1) * 64 + r;
    out[idx] = src[((size_t)n * 128 + ch) * HW + p];
}

__global__ void relu_kernel(float* __restrict__ x, long long nelem)
{
    const long long i = (long long)blockIdx.x * TPB + threadIdx.x;
    if (i < nelem) x[i] = fmaxf(x[i], 0.0f);
}

// ---------------------------------------------------------------------------
// VQ: per 64-vector tile find argmin_e (|e|^2 - 2 z.e), write q = emb[idx],
// accumulate per-block sum of |q - z|^2 into lossp[blockIdx.x].
// z,q in NCHW (C=128); HW % 64 == 0 so a tile never crosses batch.
// ---------------------------------------------------------------------------
#define VQ_TV 64
#define VQ_TE 32
__global__ void vq_kernel(const float* __restrict__ z, const float* __restrict__ emb,
                          float* __restrict__ q, float* __restrict__ lossp,
                          int HW, int Kc)
{
    __shared__ float zs[VQ_TV][129];
    __shared__ float es[VQ_TE][129];
    __shared__ float en[VQ_TE];
    __shared__ float rdd[VQ_TV][16];
    __shared__ int   rdi[VQ_TV][16];
    __shared__ int   idxv[VQ_TV];
    __shared__ float red[256];

    const int C = 128;
    const int tid = threadIdx.x;
    const long long gv0 = (long long)blockIdx.x * VQ_TV;
    const int n = (int)(gv0 / HW);
    const int p0 = (int)(gv0 - (long long)n * HW);
    const float* zb = z + (size_t)n * C * HW + p0;

    for (int i = tid; i < VQ_TV * C; i += 256) {
        const int c = i >> 6, v = i & 63;
        zs[v][c] = zb[(size_t)c * HW + v];
    }
    __syncthreads();

    const int ty = tid >> 4;   // 0..15 : quad of 4 vectors
    const int tx = tid & 15;   // 0..15 : pair of 2 embeddings
    float best[4];
    int   bidx[4];
    #pragma unroll
    for (int r = 0; r < 4; ++r) { best[r] = 1e30f; bidx[r] = 0; }

    for (int e0 = 0; e0 < Kc; e0 += VQ_TE) {
        for (int i = tid; i < VQ_TE * C; i += 256) {
            const int e = i >> 7, c = i & 127;
            es[e][c] = emb[(size_t)(e0 + e) * C + c];
        }
        __syncthreads();
        if (tid < VQ_TE) {
            float s = 0.0f;
            for (int c = 0; c < C; ++c) { const float t = es[tid][c]; s = fmaf(t, t, s); }
            en[tid] = s;
        }
        __syncthreads();

        float dot[4][2];
        #pragma unroll
        for (int r = 0; r < 4; ++r) { dot[r][0] = 0.0f; dot[r][1] = 0.0f; }
        const int vB = ty * 4, eB = tx * 2;
        for (int c = 0; c < C; ++c) {
            const float e0v = es[eB][c], e1v = es[eB + 1][c];
            #pragma unroll
            for (int r = 0; r < 4; ++r) {
                const float zv = zs[vB + r][c];
                dot[r][0] = fmaf(zv, e0v, dot[r][0]);
                dot[r][1] = fmaf(zv, e1v, dot[r][1]);
            }
        }
        #pragma unroll
        for (int r = 0; r < 4; ++r) {
            #pragma unroll
            for (int s = 0; s < 2; ++s) {
                const float d = en[eB + s] - 2.0f * dot[r][s];
                const int ei = e0 + eB + s;
                if (d < best[r]) { best[r] = d; bidx[r] = ei; }
            }
        }
        __syncthreads();
    }

    #pragma unroll
    for (int r = 0; r < 4; ++r) { rdd[ty * 4 + r][tx] = best[r]; rdi[ty * 4 + r][tx] = bidx[r]; }
    __syncthreads();
    if (tid < VQ_TV) {
        float bd = rdd[tid][0]; int bi = rdi[tid][0];
        for (int j = 1; j < 16; ++j) {
            const float d = rdd[tid][j]; const int i2 = rdi[tid][j];
            if (d < bd || (d == bd && i2 < bi)) { bd = d; bi = i2; }
        }
        idxv[tid] = bi;
    }
    __syncthreads();

    float ls = 0.0f;
    float* qb = q + (size_t)n * C * HW + p0;
    for (int i = tid; i < VQ_TV * C; i += 256) {
        const int c = i >> 6, v = i & 63;
        const float e = emb[(size_t)idxv[v] * C + c];
        qb[(size_t)c * HW + v] = e;
        const float diff = e - zs[v][c];
        ls = fmaf(diff, diff, ls);
    }
    red[tid] = ls;
    __syncthreads();
    for (int s = 128; s > 0; s >>= 1) {
        if (tid < s) red[tid] += red[tid + s];
        __syncthreads();
    }
    if (tid == 0) lossp[blockIdx.x] = red[0];
}

__global__ void loss_finish_kernel(const float* __restrict__ p, int n, float scale,
                                   float* __restrict__ out)
{
    __shared__ float red[256];
    float s = 0.0f;
    for (int i = threadIdx.x; i < n; i += 256) s += p[i];
    red[threadIdx.x] = s;
    __syncthreads();
    for (int k = 128; k > 0; k >>= 1) {
        if (threadIdx.x < k) red[threadIdx.x] += red[threadIdx.x + k];
        __syncthreads();
    }
    if (threadIdx.x == 0) out[0] = red[0] * scale;
}

// ---------------------------------------------------------------------------
// Final 1x1 heads: y2 (8,32,256,256) -> recon (8,4,256,256)
// ---------------------------------------------------------------------------
__global__ void outconv_kernel(const float* __restrict__ y,
                               const float* __restrict__ odw, const float* __restrict__ odb,
                               const float* __restrict__ orw, const float* __restrict__ orb,
                               float* __restrict__ out)
{
    const long long idx = (long long)blockIdx.x * TPB + threadIdx.x;
    const int HW = 256 * 256;
    if (idx >= 8LL * 4 * HW) return;
    const int p = (int)(idx % HW);
    const int t = (int)(idx / HW);
    const int c = t & 3, n = t >> 2;
    const float* yb = y + (size_t)n * 32 * HW + p;
    float v;
    if (c == 0) {
        v = odb[0];
        for (int k = 0; k < 16; ++k) v = fmaf(yb[(size_t)k * HW], odw[k], v);
    } else {
        const int j = c - 1;
        v = orb[j];
        for (int k = 0; k < 16; ++k) v = fmaf(yb[(size_t)(16 + k) * HW], orw[j * 16 + k], v);
    }
    out[idx] = v;
}

// ---------------------------------------------------------------------------
static inline void conv_launch(hipStream_t st, const float* in, const float* w, const float* b,
                               float* out, int Cin, int Hin, int Win, int Cout, int Hout, int Wout,
                               int K, int stride, int pad, int groups, bool reluIn, int flags)
{
    dim3 g((Hout * Wout + TPB - 1) / TPB, Cout, 8);
    if (K == 1) {
        if (reluIn) conv2d_kernel<1, true ><<<g, TPB, 0, st>>>(in, w, b, out, Cin, Hin, Win, Cout, Hout, Wout, stride, pad, groups, flags);
        else        conv2d_kernel<1, false><<<g, TPB, 0, st>>>(in, w, b, out, Cin, Hin, Win, Cout, Hout, Wout, stride, pad, groups, flags);
    } else if (K == 3) {
        if (reluIn) conv2d_kernel<3, true ><<<g, TPB, 0, st>>>(in, w, b, out, Cin, Hin, Win, Cout, Hout, Wout, stride, pad, groups, flags);
        else        conv2d_kernel<3, false><<<g, TPB, 0, st>>>(in, w, b, out, Cin, Hin, Win, Cout, Hout, Wout, stride, pad, groups, flags);
    } else {
        if (reluIn) conv2d_kernel<4, true ><<<g, TPB, 0, st>>>(in, w, b, out, Cin, Hin, Win, Cout, Hout, Wout, stride, pad, groups, flags);
        else        conv2d_kernel<4, false><<<g, TPB, 0, st>>>(in, w, b, out, Cin, Hin, Win, Cout, Hout, Wout, stride, pad, groups, flags);
    }
}

static inline void convt_launch(hipStream_t st, const float* in, const float* w, const float* b,
                                float* out, int Cin, int Hin, int Win, int Cout, int Hout, int Wout,
                                int groups, int flags)
{
    dim3 g((Hout * Wout + TPB - 1) / TPB, Cout, 8);
    convt2d_kernel<4><<<g, TPB, 0, st>>>(in, w, b, out, Cin, Hin, Win, Cout, Hout, Wout, 2, 1, groups, flags);
}

static inline void res_stack_launch(hipStream_t st, float* xbuf, float* rh,
                                    const float* w1, const float* w2, int Hs, int Ws)
{
    for (int i = 0; i < 2; ++i) {
        conv_launch(st, xbuf, w1 + (size_t)i * 64 * 64 * 9, nullptr, rh,
                    128, Hs, Ws, 64, Hs, Ws, 3, 1, 1, 2, true, 0);
        conv_launch(st, rh, w2 + (size_t)i * 128 * 32, nullptr, xbuf,
                    64, Hs, Ws, 128, Hs, Ws, 1, 1, 0, 2, true, 1);
    }
    const long long nel = 8LL * 128 * Hs * Ws;
    relu_kernel<<<(unsigned)((nel + TPB - 1) / TPB), TPB, 0, st>>>(xbuf, nel);
}

extern "C" void kernel_launch(void* const* d_in, const int* in_sizes, int n_in,
                              void* d_out, int out_size, void* d_ws, size_t ws_size,
                              hipStream_t stream)
{
    const float* x      = (const float*)d_in[0];
    const float* eb_dw  = (const float*)d_in[1];
    const float* eb_db  = (const float*)d_in[2];
    const float* eb_rw  = (const float*)d_in[3];
    const float* eb_rb  = (const float*)d_in[4];
    const float* eb_c1w = (const float*)d_in[5];
    const float* eb_c1b = (const float*)d_in[6];
    const float* eb_c2w = (const float*)d_in[7];
    const float* eb_c2b = (const float*)d_in[8];
    const float* eb_c3w = (const float*)d_in[9];
    const float* eb_c3b = (const float*)d_in[10];
    const float* eb_rw1 = (const float*)d_in[11];
    const float* eb_rw2 = (const float*)d_in[12];
    const float* et_c1w = (const float*)d_in[13];
    const float* et_c1b = (const float*)d_in[14];
    const float* et_c2w = (const float*)d_in[15];
    const float* et_c2b = (const float*)d_in[16];
    const float* et_rw1 = (const float*)d_in[17];
    const float* et_rw2 = (const float*)d_in[18];
    const float* pvt_w  = (const float*)d_in[19];
    const float* pvt_b  = (const float*)d_in[20];
    const float* up_w   = (const float*)d_in[21];
    const float* up_b   = (const float*)d_in[22];
    const float* pvb_w  = (const float*)d_in[23];
    const float* pvb_b  = (const float*)d_in[24];
    const float* emb_t  = (const float*)d_in[25];
    const float* emb_b  = (const float*)d_in[26];
    const float* db_c1w = (const float*)d_in[27];
    const float* db_c1b = (const float*)d_in[28];
    const float* db_rw1 = (const float*)d_in[29];
    const float* db_rw2 = (const float*)d_in[30];
    const float* db_t1w = (const float*)d_in[31];
    const float* db_t1b = (const float*)d_in[32];
    const float* db_t2w = (const float*)d_in[33];
    const float* db_t2b = (const float*)d_in[34];
    const float* db_odw = (const float*)d_in[35];
    const float* db_odb = (const float*)d_in[36];
    const float* db_orw = (const float*)d_in[37];
    const float* db_orb = (const float*)d_in[38];

    float* ws  = (float*)d_ws;
    float* out = (float*)d_out;

    // ---- workspace arena (float offsets, liveness-based reuse) ----
    const size_t OFF_H0   = 0;          // (8, 64,256,256) 33554432
    const size_t OFF_H1   = 33554432;   // (8, 64,128,128)  8388608
    const size_t OFF_H2   = 0;          // (8,128, 64, 64)  4194304  (h0 dead)
    const size_t OFF_ENCB = 4194304;    // (8,128, 64, 64)  4194304
    const size_t OFF_RH   = 8388608;    // (8, 64, 64, 64)  2097152  (res tmp, reused)
    const size_t OFF_T1   = 10485760;   // (8,128, 32, 32)  1048576
    const size_t OFF_T2   = 11534336;   // (8,128, 32, 32)  1048576
    const size_t OFF_ZT   = 12582912;   // (8,128, 32, 32)  1048576
    const size_t OFF_UPT  = 13631488;   // (8,128, 64, 64)  4194304
    const size_t OFF_JOIN = 17825792;   // (8,256, 64, 64)  8388608
    const size_t OFF_ZB   = 26214400;   // (8,128, 64, 64)  4194304
    const size_t OFF_DJ   = 0;          // (8,256, 64, 64)  8388608  (enc dead)
    const size_t OFF_Y    = 26214400;   // (8,128, 64, 64)  4194304  (zb dead)
    const size_t OFF_Y1   = 10485760;   // (8, 64,128,128)  8388608  (t/zt/upt dead)
    const size_t OFF_Y2   = 18874368;   // (8, 32,256,256) 16777216  (join/zb/y dead)
    const size_t OFF_LPT  = 41943040;   // 128 loss partials (top)
    const size_t OFF_LPB  = 41943168;   // 512 loss partials (bot)
    const size_t NEED     = 41943680;   // floats
    if (ws_size < NEED * sizeof(float)) return;   // insufficient scratch

    // ---- output layout: loss_b, loss_t, recon, q_t, q_b ----
    float* o_loss_b = out + 0;
    float* o_loss_t = out + 1;
    float* o_recon  = out + 2;
    float* o_qt     = out + 2 + 8 * 4 * 65536;                 // 2097154
    float* o_qb     = o_qt + 8 * 128 * 1024;                   // +1048576

    // ===== EncoderBot =====
    {   // fused 1x1 depth/rgb heads + relu -> h0 (8,64,256,256)
        const long long nel = 8LL * 64 * 65536;
        head_kernel<<<(unsigned)((nel + TPB - 1) / TPB), TPB, 0, stream>>>(
            x, eb_dw, eb_db, eb_rw, eb_rb, ws + OFF_H0);
    }
    conv_launch(stream, ws + OFF_H0, eb_c1w, eb_c1b, ws + OFF_H1,
                64, 256, 256, 64, 128, 128, 4, 2, 1, 2, false, 2);      // relu
    conv_launch(stream, ws + OFF_H1, eb_c2w, eb_c2b, ws + OFF_H2,
                64, 128, 128, 128, 64, 64, 4, 2, 1, 2, false, 2);       // relu
    conv_launch(stream, ws + OFF_H2, eb_c3w, eb_c3b, ws + OFF_ENCB,
                128, 64, 64, 128, 64, 64, 3, 1, 1, 2, false, 0);
    res_stack_launch(stream, ws + OFF_ENCB, ws + OFF_RH, eb_rw1, eb_rw2, 64, 64);

    // ===== EncoderTop =====
    conv_launch(stream, ws + OFF_ENCB, et_c1w, et_c1b, ws + OFF_T1,
                128, 64, 64, 128, 32, 32, 4, 2, 1, 2, false, 2);        // relu
    conv_launch(stream, ws + OFF_T1, et_c2w, et_c2b, ws + OFF_T2,
                128, 32, 32, 128, 32, 32, 3, 1, 1, 2, false, 2);        // relu
    res_stack_launch(stream, ws + OFF_T2, ws + OFF_RH, et_rw1, et_rw2, 32, 32);

    // ===== top VQ =====
    conv_launch(stream, ws + OFF_T2, pvt_w, pvt_b, ws + OFF_ZT,
                128, 32, 32, 128, 32, 32, 1, 1, 0, 2, false, 0);
    vq_kernel<<<128, 256, 0, stream>>>(ws + OFF_ZT, emb_t, o_qt, ws + OFF_LPT, 1024, 2048);
    loss_finish_kernel<<<1, 256, 0, stream>>>(ws + OFF_LPT, 128, 0.25f / (8192.0f * 128.0f), o_loss_t);

    // up_t = conv_t(q_t) -> (8,128,64,64)
    convt_launch(stream, o_qt, up_w, up_b, ws + OFF_UPT, 128, 32, 32, 128, 64, 64, 2, 0);

    // ===== PreVQBot / bottom VQ =====
    {
        const long long nel = 8LL * 256 * 4096;
        regroup_kernel<<<(unsigned)((nel + TPB - 1) / TPB), TPB, 0, stream>>>(
            ws + OFF_ENCB, ws + OFF_UPT, ws + OFF_JOIN, 4096);
    }
    conv_launch(stream, ws + OFF_JOIN, pvb_w, pvb_b, ws + OFF_ZB,
                256, 64, 64, 128, 64, 64, 1, 1, 0, 2, false, 0);
    vq_kernel<<<512, 256, 0, stream>>>(ws + OFF_ZB, emb_b, o_qb, ws + OFF_LPB, 4096, 2048);
    loss_finish_kernel<<<1, 256, 0, stream>>>(ws + OFF_LPB, 512, 0.25f / (32768.0f * 128.0f), o_loss_b);

    // ===== DecoderBot =====
    {
        const long long nel = 8LL * 256 * 4096;
        regroup_kernel<<<(unsigned)((nel + TPB - 1) / TPB), TPB, 0, stream>>>(
            ws + OFF_UPT, o_qb, ws + OFF_DJ, 4096);
    }
    conv_launch(stream, ws + OFF_DJ, db_c1w, db_c1b, ws + OFF_Y,
                256, 64, 64, 128, 64, 64, 3, 1, 1, 2, false, 0);
    res_stack_launch(stream, ws + OFF_Y, ws + OFF_RH, db_rw1, db_rw2, 64, 64);
    convt_launch(stream, ws + OFF_Y, db_t1w, db_t1b, ws + OFF_Y1,
                 128, 64, 64, 64, 128, 128, 2, 2);                      // relu
    convt_launch(stream, ws + OFF_Y1, db_t2w, db_t2b, ws + OFF_Y2,
                 64, 128, 128, 32, 256, 256, 2, 0);                     // no relu
    {
        const long long nel = 8LL * 4 * 65536;
        outconv_kernel<<<(unsigned)((nel + TPB - 1) / TPB), TPB, 0, stream>>>(
            ws + OFF_Y2, db_odw, db_odb, db_orw, db_orb, o_recon);
    }
}

// Round 2
// 2943.730 us; speedup vs baseline: 3.6708x; 3.6708x over previous
//
#include <hip/hip_runtime.h>
#include <cstddef>

#define TPB 256

// ===========================================================================
// Tiled 3x3 stride-1 pad-1 grouped conv (groups=2, square images, W in {32,64})
// Block: 256 thr = 64 px-lanes x 4 oc-quads; thread computes 8 oc x 4 px.
// ===========================================================================
template<int W, bool RELU_IN>
__global__ __launch_bounds__(256) void conv3_kernel(
    const float* __restrict__ in, const float* __restrict__ wgt,
    const float* __restrict__ bias, float* __restrict__ out,
    int Cin, int Cout, int relu_out)
{
    constexpr int ROWS = 256 / W;
    constexpr int ICB  = 8;
    constexpr int IN_H = ROWS + 2, IN_W = W + 2;
    __shared__ float s_in[ICB][IN_H][IN_W];
    __shared__ float s_w[ICB * 9 * 32];

    const int tid = threadIdx.x;
    const int tx = tid & 63, ty = tid >> 6;
    const int n  = blockIdx.z;
    const int oc0 = blockIdx.y * 32;
    const int r0  = blockIdx.x * ROWS;
    const int icg = Cin >> 1, ocg = Cout >> 1;
    const int g = oc0 / ocg;

    float acc[8][4];
    #pragma unroll
    for (int o = 0; o < 8; ++o) {
        const float b = bias ? bias[oc0 + ty * 8 + o] : 0.0f;
        #pragma unroll
        for (int j = 0; j < 4; ++j) acc[o][j] = b;
    }

    const float* inb = in + ((size_t)n * Cin + (size_t)g * icg) * (W * W);
    for (int ic0 = 0; ic0 < icg; ic0 += ICB) {
        __syncthreads();
        for (int i = tid; i < ICB * IN_H * IN_W; i += 256) {
            const int icl = i / (IN_H * IN_W);
            const int rem = i - icl * (IN_H * IN_W);
            const int rr = rem / IN_W, cc = rem - rr * IN_W;
            const int y = r0 - 1 + rr, x = cc - 1;
            float v = 0.0f;
            if ((unsigned)y < (unsigned)W && (unsigned)x < (unsigned)W)
                v = inb[(size_t)(ic0 + icl) * (W * W) + y * W + x];
            if (RELU_IN) v = fmaxf(v, 0.0f);
            s_in[icl][rr][cc] = v;
        }
        for (int i = tid; i < ICB * 9 * 32; i += 256) {
            const int ocl = i & 31;
            const int rest = i >> 5;
            const int k = rest % 9, icl = rest / 9;
            s_w[i] = wgt[((size_t)(oc0 + ocl) * icg + (ic0 + icl)) * 9 + k];
        }
        __syncthreads();

        #pragma unroll 1
        for (int icl = 0; icl < ICB; ++icl) {
            const float* swb = s_w + icl * 288 + ty * 8;
            #pragma unroll
            for (int ky = 0; ky < 3; ++ky) {
                #pragma unroll
                for (int kx = 0; kx < 3; ++kx) {
                    const int kq = ky * 3 + kx;
                    const float4 wA = *(const float4*)(swb + kq * 32);
                    const float4 wB = *(const float4*)(swb + kq * 32 + 4);
                    #pragma unroll
                    for (int j = 0; j < 4; ++j) {
                        const int p = j * 64 + tx;
                        const int rr = p / W, cc = p - rr * W;
                        const float v = s_in[icl][rr + ky][cc + kx];
                        acc[0][j] = fmaf(wA.x, v, acc[0][j]);
                        acc[1][j] = fmaf(wA.y, v, acc[1][j]);
                        acc[2][j] = fmaf(wA.z, v, acc[2][j]);
                        acc[3][j] = fmaf(wA.w, v, acc[3][j]);
                        acc[4][j] = fmaf(wB.x, v, acc[4][j]);
                        acc[5][j] = fmaf(wB.y, v, acc[5][j]);
                        acc[6][j] = fmaf(wB.z, v, acc[6][j]);
                        acc[7][j] = fmaf(wB.w, v, acc[7][j]);
                    }
                }
            }
        }
    }

    const int HWo = W * W;
    float* ob = out + ((size_t)n * Cout + oc0 + ty * 8) * HWo;
    #pragma unroll
    for (int o = 0; o < 8; ++o) {
        #pragma unroll
        for (int j = 0; j < 4; ++j) {
            const int p = j * 64 + tx;
            const int rr = p / W, cc = p - rr * W;
            float r = acc[o][j];
            if (relu_out) r = fmaxf(r, 0.0f);
            ob[(size_t)o * HWo + (size_t)(r0 + rr) * W + cc] = r;
        }
    }
}

// ===========================================================================
// Tiled 4x4 stride-2 pad-1 grouped conv (groups=2). W = OUTPUT width (square);
// input is 2W x 2W. Same 8 oc x 4 px register tile.
// ===========================================================================
template<int W>
__global__ __launch_bounds__(256) void conv4s2_kernel(
    const float* __restrict__ in, const float* __restrict__ wgt,
    const float* __restrict__ bias, float* __restrict__ out,
    int Cin, int Cout, int relu_out)
{
    constexpr int ROWS = 256 / W;
    constexpr int ICB  = 4;
    constexpr int IN_H = 2 * ROWS + 2, IN_W = 2 * W + 2;
    __shared__ float s_in[ICB][IN_H][IN_W];
    __shared__ float s_w[ICB * 16 * 32];

    const int tid = threadIdx.x;
    const int tx = tid & 63, ty = tid >> 6;
    const int n  = blockIdx.z;
    const int oc0 = blockIdx.y * 32;
    const int r0  = blockIdx.x * ROWS;
    const int icg = Cin >> 1, ocg = Cout >> 1;
    const int g = oc0 / ocg;
    const int Hin = 2 * W;

    float acc[8][4];
    #pragma unroll
    for (int o = 0; o < 8; ++o) {
        const float b = bias ? bias[oc0 + ty * 8 + o] : 0.0f;
        #pragma unroll
        for (int j = 0; j < 4; ++j) acc[o][j] = b;
    }

    const float* inb = in + ((size_t)n * Cin + (size_t)g * icg) * (Hin * Hin);
    for (int ic0 = 0; ic0 < icg; ic0 += ICB) {
        __syncthreads();
        for (int i = tid; i < ICB * IN_H * IN_W; i += 256) {
            const int icl = i / (IN_H * IN_W);
            const int rem = i - icl * (IN_H * IN_W);
            const int rr = rem / IN_W, cc = rem - rr * IN_W;
            const int y = 2 * r0 - 1 + rr, x = cc - 1;
            float v = 0.0f;
            if ((unsigned)y < (unsigned)Hin && (unsigned)x < (unsigned)Hin)
                v = inb[(size_t)(ic0 + icl) * (Hin * Hin) + y * Hin + x];
            s_in[icl][rr][cc] = v;
        }
        for (int i = tid; i < ICB * 16 * 32; i += 256) {
            const int ocl = i & 31;
            const int rest = i >> 5;
            const int k = rest & 15, icl = rest >> 4;
            s_w[i] = wgt[((size_t)(oc0 + ocl) * icg + (ic0 + icl)) * 16 + k];
        }
        __syncthreads();

        #pragma unroll 1
        for (int icl = 0; icl < ICB; ++icl) {
            const float* swb = s_w + icl * 512 + ty * 8;
            #pragma unroll
            for (int ky = 0; ky < 4; ++ky) {
                #pragma unroll
                for (int kx = 0; kx < 4; ++kx) {
                    const int kq = ky * 4 + kx;
                    const float4 wA = *(const float4*)(swb + kq * 32);
                    const float4 wB = *(const float4*)(swb + kq * 32 + 4);
                    #pragma unroll
                    for (int j = 0; j < 4; ++j) {
                        const int p = j * 64 + tx;
                        const int rr = p / W, cc = p - rr * W;
                        const float v = s_in[icl][2 * rr + ky][2 * cc + kx];
                        acc[0][j] = fmaf(wA.x, v, acc[0][j]);
                        acc[1][j] = fmaf(wA.y, v, acc[1][j]);
                        acc[2][j] = fmaf(wA.z, v, acc[2][j]);
                        acc[3][j] = fmaf(wA.w, v, acc[3][j]);
                        acc[4][j] = fmaf(wB.x, v, acc[4][j]);
                        acc[5][j] = fmaf(wB.y, v, acc[5][j]);
                        acc[6][j] = fmaf(wB.z, v, acc[6][j]);
                        acc[7][j] = fmaf(wB.w, v, acc[7][j]);
                    }
                }
            }
        }
    }

    const int HWo = W * W;
    float* ob = out + ((size_t)n * Cout + oc0 + ty * 8) * HWo;
    #pragma unroll
    for (int o = 0; o < 8; ++o) {
        #pragma unroll
        for (int j = 0; j < 4; ++j) {
            const int p = j * 64 + tx;
            const int rr = p / W, cc = p - rr * W;
            float r = acc[o][j];
            if (relu_out) r = fmaxf(r, 0.0f);
            ob[(size_t)o * HWo + (size_t)(r0 + rr) * W + cc] = r;
        }
    }
}

// ===========================================================================
// Tiled 1x1 grouped conv (pure GEMM over pixels). 256 px x 32 oc per block.
// ===========================================================================
template<bool RELU_IN, bool ACC, bool RELU_OUT>
__global__ __launch_bounds__(256) void conv1_kernel(
    const float* __restrict__ in, const float* __restrict__ wgt,
    const float* __restrict__ bias, float* __restrict__ out,
    int Cin, int Cout, int HW)
{
    constexpr int ICB = 16;
    __shared__ float s_in[ICB][256];
    __shared__ float s_w[ICB * 32];

    const int tid = threadIdx.x;
    const int tx = tid & 63, ty = tid >> 6;
    const int n  = blockIdx.z;
    const int oc0 = blockIdx.y * 32;
    const int p0  = blockIdx.x * 256;
    const int icg = Cin >> 1, ocg = Cout >> 1;
    const int g = oc0 / ocg;

    float acc[8][4];
    #pragma unroll
    for (int o = 0; o < 8; ++o) {
        const float b = bias ? bias[oc0 + ty * 8 + o] : 0.0f;
        #pragma unroll
        for (int j = 0; j < 4; ++j) acc[o][j] = b;
    }

    const float* inb = in + ((size_t)n * Cin + (size_t)g * icg) * HW + p0;
    for (int ic0 = 0; ic0 < icg; ic0 += ICB) {
        __syncthreads();
        for (int i = tid; i < ICB * 256; i += 256) {
            const int icl = i >> 8, p = i & 255;
            float v = inb[(size_t)(ic0 + icl) * HW + p];
            if (RELU_IN) v = fmaxf(v, 0.0f);
            s_in[icl][p] = v;
        }
        for (int i = tid; i < ICB * 32; i += 256) {
            const int ocl = i & 31, icl = i >> 5;
            s_w[i] = wgt[(size_t)(oc0 + ocl) * icg + ic0 + icl];
        }
        __syncthreads();

        #pragma unroll 4
        for (int icl = 0; icl < ICB; ++icl) {
            const float4 wA = *(const float4*)(s_w + icl * 32 + ty * 8);
            const float4 wB = *(const float4*)(s_w + icl * 32 + ty * 8 + 4);
            #pragma unroll
            for (int j = 0; j < 4; ++j) {
                const float v = s_in[icl][j * 64 + tx];
                acc[0][j] = fmaf(wA.x, v, acc[0][j]);
                acc[1][j] = fmaf(wA.y, v, acc[1][j]);
                acc[2][j] = fmaf(wA.z, v, acc[2][j]);
                acc[3][j] = fmaf(wA.w, v, acc[3][j]);
                acc[4][j] = fmaf(wB.x, v, acc[4][j]);
                acc[5][j] = fmaf(wB.y, v, acc[5][j]);
                acc[6][j] = fmaf(wB.z, v, acc[6][j]);
                acc[7][j] = fmaf(wB.w, v, acc[7][j]);
            }
        }
    }

    float* ob = out + ((size_t)n * Cout + oc0 + ty * 8) * HW + p0;
    #pragma unroll
    for (int o = 0; o < 8; ++o) {
        #pragma unroll
        for (int j = 0; j < 4; ++j) {
            const size_t idx = (size_t)o * HW + j * 64 + tx;
            float r = acc[o][j];
            if (ACC) r += ob[idx];
            if (RELU_OUT) r = fmaxf(r, 0.0f);
            ob[idx] = r;
        }
    }
}

// ===========================================================================
// Tiled grouped ConvTranspose2d K4 s2 p1 (groups=2). W = OUTPUT width; input
// W/2 x W/2. torch layout w: (Cin, Cout/groups, 4, 4). Parity-decomposed taps.
// ===========================================================================
template<int W, int ROWS, int OCT>
__global__ __launch_bounds__(64 * (OCT / 8)) void convt4_kernel(
    const float* __restrict__ in, const float* __restrict__ wgt,
    const float* __restrict__ bias, float* __restrict__ out,
    int Cin, int Cout, int relu_out)
{
    constexpr int NTHR = 64 * (OCT / 8);
    constexpr int PXT  = ROWS * W / 64;
    constexpr int WP   = W / 64;            // px-cols per 64-lane stripe
    constexpr int ICB  = 8;
    constexpr int RIN  = ((ROWS + 1) >> 1) + 2;
    constexpr int CIN  = W / 2 + 2;
    __shared__ float s_in[ICB][RIN][CIN];
    __shared__ float s_w[ICB * 16 * OCT];

    const int tid = threadIdx.x;
    const int tx = tid & 63, ty = tid >> 6;
    const int n  = blockIdx.z;
    const int oc0 = blockIdx.y * OCT;
    const int r0  = blockIdx.x * ROWS;      // even (ROWS even)
    const int icg = Cin >> 1, ocg = Cout >> 1;
    const int g = oc0 / ocg, of0 = oc0 - g * ocg;
    const int Hin = W / 2;
    const int iy_lo = (r0 - 2) >> 1;

    float acc[8][PXT];
    #pragma unroll
    for (int o = 0; o < 8; ++o) {
        const float b = bias ? bias[oc0 + ty * 8 + o] : 0.0f;
        #pragma unroll
        for (int j = 0; j < PXT; ++j) acc[o][j] = b;
    }

    const float* inb = in + ((size_t)n * Cin + (size_t)g * icg) * (Hin * Hin);
    const int kxl = ((tx + 1) & 1);          // base kx parity for this lane
    const int hx  = (tx + 1) >> 1;

    for (int ic0 = 0; ic0 < icg; ic0 += ICB) {
        __syncthreads();
        for (int i = tid; i < ICB * RIN * CIN; i += NTHR) {
            const int icl = i / (RIN * CIN);
            const int rem = i - icl * (RIN * CIN);
            const int rr = rem / CIN, cc = rem - rr * CIN;
            const int y = iy_lo + rr, x = cc - 1;
            float v = 0.0f;
            if ((unsigned)y < (unsigned)Hin && (unsigned)x < (unsigned)Hin)
                v = inb[(size_t)(ic0 + icl) * (Hin * Hin) + y * Hin + x];
            s_in[icl][rr][cc] = v;
        }
        for (int i = tid; i < ICB * 16 * OCT; i += NTHR) {
            const int ocl = i & (OCT - 1);
            const int rest = i / OCT;
            const int k = rest & 15, icl = rest >> 4;
            s_w[i] = wgt[((size_t)(g * icg + ic0 + icl) * ocg + of0 + ocl) * 16 + k];
        }
        __syncthreads();

        #pragma unroll 1
        for (int icl = 0; icl < ICB; ++icl) {
            const float* swb = s_w + icl * 16 * OCT + ty * 8;
            #pragma unroll
            for (int tt = 0; tt < 4; ++tt) {
                const int ty2 = tt >> 1, tx2 = tt & 1;
                float4 wp0[2], wp1[2];
                #pragma unroll
                for (int par = 0; par < 2; ++par) {
                    const int koff = ((2 * ty2 + par) * 4 + (kxl + 2 * tx2)) * OCT;
                    wp0[par] = *(const float4*)(swb + koff);
                    wp1[par] = *(const float4*)(swb + koff + 4);
                }
                const int cbase = hx - tx2 + 1;
                #pragma unroll
                for (int j = 0; j < PXT; ++j) {
                    const int row_j = j / WP, m_j = j - row_j * WP;
                    const int pj = (row_j + 1) & 1;              // r0 even
                    const int rloc = (row_j + 1 - pj) / 2 - ty2 + 1;
                    const float v = s_in[icl][rloc][32 * m_j + cbase];
                    const float4 wa = pj ? wp0[1] : wp0[0];
                    const float4 wb = pj ? wp1[1] : wp1[0];
                    acc[0][j] = fmaf(wa.x, v, acc[0][j]);
                    acc[1][j] = fmaf(wa.y, v, acc[1][j]);
                    acc[2][j] = fmaf(wa.z, v, acc[2][j]);
                    acc[3][j] = fmaf(wa.w, v, acc[3][j]);
                    acc[4][j] = fmaf(wb.x, v, acc[4][j]);
                    acc[5][j] = fmaf(wb.y, v, acc[5][j]);
                    acc[6][j] = fmaf(wb.z, v, acc[6][j]);
                    acc[7][j] = fmaf(wb.w, v, acc[7][j]);
                }
            }
        }
    }

    const int HWo = W * W;
    float* ob = out + ((size_t)n * Cout + oc0 + ty * 8) * HWo;
    #pragma unroll
    for (int o = 0; o < 8; ++o) {
        #pragma unroll
        for (int j = 0; j < PXT; ++j) {
            const int row_j = j / WP, m_j = j - row_j * WP;
            float r = acc[o][j];
            if (relu_out) r = fmaxf(r, 0.0f);
            ob[(size_t)o * HWo + (size_t)(r0 + row_j) * W + 64 * m_j + tx] = r;
        }
    }
}

// ===========================================================================
// Fused encoder head: relu(concat(1x1(x[:, :1], dw), 1x1(x[:, 1:], rw)))
// ===========================================================================
__global__ void head_kernel(const float* __restrict__ x,
                            const float* __restrict__ dw, const float* __restrict__ db,
                            const float* __restrict__ rw, const float* __restrict__ rb,
                            float* __restrict__ out)
{
    const long long idx = (long long)blockIdx.x * TPB + threadIdx.x;
    const int HW = 256 * 256;
    if (idx >= 8LL * 64 * HW) return;
    const int p = (int)(idx % HW);
    const int t = (int)(idx / HW);
    const int c = t & 63, n = t >> 6;
    const float* xb = x + (size_t)n * 4 * HW;
    float v;
    if (c < 32) {
        v = fmaf(xb[p], dw[c], db[c]);
    } else {
        const int cc = c - 32;
        v = rb[cc];
        v = fmaf(xb[(size_t)HW + p],     rw[cc * 3 + 0], v);
        v = fmaf(xb[(size_t)2 * HW + p], rw[cc * 3 + 1], v);
        v = fmaf(xb[(size_t)3 * HW + p], rw[cc * 3 + 2], v);
    }
    out[idx] = fmaxf(v, 0.0f);
}

// Channel regroup: out(8,256,HW) = cat(a[:64], b[:64], a[64:], b[64:]) per n.
__global__ void regroup_kernel(const float* __restrict__ a, const float* __restrict__ b,
                               float* __restrict__ out, int HW)
{
    const long long idx = (long long)blockIdx.x * TPB + threadIdx.x;
    const long long total = 8LL * 256 * HW;
    if (idx >= total) return;
    const int p = (int)(idx % HW);
    const int t = (int)(idx / HW);
    const int c = t & 255, n = t >> 8;
    const int q = c >> 6, r = c & 63;
    const float* src = (q & 1) ? b : a;
    const int ch = (q >> 1) * 64 + r;
    out[idx] = src[((size_t)n * 128 + ch) * HW + p];
}

// Precompute |emb_k|^2
__global__ void emb_norm_kernel(const float* __restrict__ emb, float* __restrict__ en, int K)
{
    const int k = blockIdx.x * TPB + threadIdx.x;
    if (k >= K) return;
    const float* e = emb + (size_t)k * 128;
    float s = 0.0f;
    for (int c = 0; c < 128; ++c) s = fmaf(e[c], e[c], s);
    en[k] = s;
}

// ===========================================================================
// VQ: per 64-vector tile argmin_e (|e|^2 - 2 z.e); q = emb[idx]; per-block
// partial sum of |q - z|^2.
// ===========================================================================
#define VQ_TV 64
#define VQ_TE 32
__global__ void vq_kernel(const float* __restrict__ z, const float* __restrict__ emb,
                          const float* __restrict__ en_g,
                          float* __restrict__ q, float* __restrict__ lossp,
                          int HW, int Kc)
{
    __shared__ float zs[VQ_TV][129];
    __shared__ float es[VQ_TE][129];
    __shared__ float en[VQ_TE];
    __shared__ float rdd[VQ_TV][16];
    __shared__ int   rdi[VQ_TV][16];
    __shared__ int   idxv[VQ_TV];
    __shared__ float red[256];

    const int C = 128;
    const int tid = threadIdx.x;
    const long long gv0 = (long long)blockIdx.x * VQ_TV;
    const int n = (int)(gv0 / HW);
    const int p0 = (int)(gv0 - (long long)n * HW);
    const float* zb = z + (size_t)n * C * HW + p0;

    for (int i = tid; i < VQ_TV * C; i += 256) {
        const int c = i >> 6, v = i & 63;
        zs[v][c] = zb[(size_t)c * HW + v];
    }
    __syncthreads();

    const int ty = tid >> 4;
    const int tx = tid & 15;
    float best[4];
    int   bidx[4];
    #pragma unroll
    for (int r = 0; r < 4; ++r) { best[r] = 1e30f; bidx[r] = 0; }

    for (int e0 = 0; e0 < Kc; e0 += VQ_TE) {
        for (int i = tid; i < VQ_TE * C; i += 256) {
            const int e = i >> 7, c = i & 127;
            es[e][c] = emb[(size_t)(e0 + e) * C + c];
        }
        if (tid < VQ_TE) en[tid] = en_g[e0 + tid];
        __syncthreads();

        float dot[4][2];
        #pragma unroll
        for (int r = 0; r < 4; ++r) { dot[r][0] = 0.0f; dot[r][1] = 0.0f; }
        const int vB = ty * 4, eB = tx * 2;
        for (int c = 0; c < C; ++c) {
            const float e0v = es[eB][c], e1v = es[eB + 1][c];
            #pragma unroll
            for (int r = 0; r < 4; ++r) {
                const float zv = zs[vB + r][c];
                dot[r][0] = fmaf(zv, e0v, dot[r][0]);
                dot[r][1] = fmaf(zv, e1v, dot[r][1]);
            }
        }
        #pragma unroll
        for (int r = 0; r < 4; ++r) {
            #pragma unroll
            for (int s = 0; s < 2; ++s) {
                const float d = en[eB + s] - 2.0f * dot[r][s];
                const int ei = e0 + eB + s;
                if (d < best[r]) { best[r] = d; bidx[r] = ei; }
            }
        }
        __syncthreads();
    }

    #pragma unroll
    for (int r = 0; r < 4; ++r) { rdd[ty * 4 + r][tx] = best[r]; rdi[ty * 4 + r][tx] = bidx[r]; }
    __syncthreads();
    if (tid < VQ_TV) {
        float bd = rdd[tid][0]; int bi = rdi[tid][0];
        for (int j = 1; j < 16; ++j) {
            const float d = rdd[tid][j]; const int i2 = rdi[tid][j];
            if (d < bd || (d == bd && i2 < bi)) { bd = d; bi = i2; }
        }
        idxv[tid] = bi;
    }
    __syncthreads();

    float ls = 0.0f;
    float* qb = q + (size_t)n * C * HW + p0;
    for (int i = tid; i < VQ_TV * C; i += 256) {
        const int c = i >> 6, v = i & 63;
        const float e = emb[(size_t)idxv[v] * C + c];
        qb[(size_t)c * HW + v] = e;
        const float diff = e - zs[v][c];
        ls = fmaf(diff, diff, ls);
    }
    red[tid] = ls;
    __syncthreads();
    for (int s = 128; s > 0; s >>= 1) {
        if (tid < s) red[tid] += red[tid + s];
        __syncthreads();
    }
    if (tid == 0) lossp[blockIdx.x] = red[0];
}

__global__ void loss_finish_kernel(const float* __restrict__ p, int n, float scale,
                                   float* __restrict__ out)
{
    __shared__ float red[256];
    float s = 0.0f;
    for (int i = threadIdx.x; i < n; i += 256) s += p[i];
    red[threadIdx.x] = s;
    __syncthreads();
    for (int k = 128; k > 0; k >>= 1) {
        if (threadIdx.x < k) red[threadIdx.x] += red[threadIdx.x + k];
        __syncthreads();
    }
    if (threadIdx.x == 0) out[0] = red[0] * scale;
}

// Final 1x1 heads: y2 (8,32,256,256) -> recon (8,4,256,256)
__global__ void outconv_kernel(const float* __restrict__ y,
                               const float* __restrict__ odw, const float* __restrict__ odb,
                               const float* __restrict__ orw, const float* __restrict__ orb,
                               float* __restrict__ out)
{
    const long long idx = (long long)blockIdx.x * TPB + threadIdx.x;
    const int HW = 256 * 256;
    if (idx >= 8LL * 4 * HW) return;
    const int p = (int)(idx % HW);
    const int t = (int)(idx / HW);
    const int c = t & 3, n = t >> 2;
    const float* yb = y + (size_t)n * 32 * HW + p;
    float v;
    if (c == 0) {
        v = odb[0];
        for (int k = 0; k < 16; ++k) v = fmaf(yb[(size_t)k * HW], odw[k], v);
    } else {
        const int j = c - 1;
        v = orb[j];
        for (int k = 0; k < 16; ++k) v = fmaf(yb[(size_t)(16 + k) * HW], orw[j * 16 + k], v);
    }
    out[idx] = v;
}

extern "C" void kernel_launch(void* const* d_in, const int* in_sizes, int n_in,
                              void* d_out, int out_size, void* d_ws, size_t ws_size,
                              hipStream_t stream)
{
    const float* x      = (const float*)d_in[0];
    const float* eb_dw  = (const float*)d_in[1];
    const float* eb_db  = (const float*)d_in[2];
    const float* eb_rw  = (const float*)d_in[3];
    const float* eb_rb  = (const float*)d_in[4];
    const float* eb_c1w = (const float*)d_in[5];
    const float* eb_c1b = (const float*)d_in[6];
    const float* eb_c2w = (const float*)d_in[7];
    const float* eb_c2b = (const float*)d_in[8];
    const float* eb_c3w = (const float*)d_in[9];
    const float* eb_c3b = (const float*)d_in[10];
    const float* eb_rw1 = (const float*)d_in[11];
    const float* eb_rw2 = (const float*)d_in[12];
    const float* et_c1w = (const float*)d_in[13];
    const float* et_c1b = (const float*)d_in[14];
    const float* et_c2w = (const float*)d_in[15];
    const float* et_c2b = (const float*)d_in[16];
    const float* et_rw1 = (const float*)d_in[17];
    const float* et_rw2 = (const float*)d_in[18];
    const float* pvt_w  = (const float*)d_in[19];
    const float* pvt_b  = (const float*)d_in[20];
    const float* up_w   = (const float*)d_in[21];
    const float* up_b   = (const float*)d_in[22];
    const float* pvb_w  = (const float*)d_in[23];
    const float* pvb_b  = (const float*)d_in[24];
    const float* emb_t  = (const float*)d_in[25];
    const float* emb_b  = (const float*)d_in[26];
    const float* db_c1w = (const float*)d_in[27];
    const float* db_c1b = (const float*)d_in[28];
    const float* db_rw1 = (const float*)d_in[29];
    const float* db_rw2 = (const float*)d_in[30];
    const float* db_t1w = (const float*)d_in[31];
    const float* db_t1b = (const float*)d_in[32];
    const float* db_t2w = (const float*)d_in[33];
    const float* db_t2b = (const float*)d_in[34];
    const float* db_odw = (const float*)d_in[35];
    const float* db_odb = (const float*)d_in[36];
    const float* db_orw = (const float*)d_in[37];
    const float* db_orb = (const float*)d_in[38];

    float* ws  = (float*)d_ws;
    float* out = (float*)d_out;

    // ---- workspace arena (float offsets, liveness-based reuse) ----
    const size_t OFF_H0   = 0;          // (8, 64,256,256)
    const size_t OFF_H1   = 33554432;   // (8, 64,128,128)
    const size_t OFF_H2   = 0;          // (8,128, 64, 64)   (h0 dead)
    const size_t OFF_ENCB = 4194304;    // (8,128, 64, 64)
    const size_t OFF_RH   = 8388608;    // (8, 64, 64, 64)   res tmp
    const size_t OFF_T1   = 10485760;   // (8,128, 32, 32)
    const size_t OFF_T2   = 11534336;   // (8,128, 32, 32)
    const size_t OFF_ZT   = 12582912;   // (8,128, 32, 32)
    const size_t OFF_UPT  = 13631488;   // (8,128, 64, 64)
    const size_t OFF_JOIN = 17825792;   // (8,256, 64, 64)
    const size_t OFF_ZB   = 26214400;   // (8,128, 64, 64)
    const size_t OFF_DJ   = 0;          // (8,256, 64, 64)   (enc dead)
    const size_t OFF_Y    = 26214400;   // (8,128, 64, 64)   (zb dead)
    const size_t OFF_Y1   = 10485760;   // (8, 64,128,128)   (t/zt/upt dead)
    const size_t OFF_Y2   = 18874368;   // (8, 32,256,256)   (join/zb/y dead)
    const size_t OFF_ENT  = 30408704;   // 2048 |emb_t|^2    (dead zone until Y2)
    const size_t OFF_ENB  = 30410752;   // 2048 |emb_b|^2
    const size_t OFF_LPT  = 41943040;   // 128 loss partials (top)
    const size_t OFF_LPB  = 41943168;   // 512 loss partials (bot)
    const size_t NEED     = 41943680;
    if (ws_size < NEED * sizeof(float)) return;

    // ---- output layout: loss_b, loss_t, recon, q_t, q_b ----
    float* o_loss_b = out + 0;
    float* o_loss_t = out + 1;
    float* o_recon  = out + 2;
    float* o_qt     = out + 2 + 8 * 4 * 65536;
    float* o_qb     = o_qt + 8 * 128 * 1024;

    // ===== EncoderBot =====
    {
        const long long nel = 8LL * 64 * 65536;
        head_kernel<<<(unsigned)((nel + TPB - 1) / TPB), TPB, 0, stream>>>(
            x, eb_dw, eb_db, eb_rw, eb_rb, ws + OFF_H0);
    }
    conv4s2_kernel<128><<<dim3(64, 2, 8), 256, 0, stream>>>(
        ws + OFF_H0, eb_c1w, eb_c1b, ws + OFF_H1, 64, 64, 1);
    conv4s2_kernel<64><<<dim3(16, 4, 8), 256, 0, stream>>>(
        ws + OFF_H1, eb_c2w, eb_c2b, ws + OFF_H2, 64, 128, 1);
    // h0 dead now: precompute embedding norms (region overlaps h0 tail)
    emb_norm_kernel<<<8, TPB, 0, stream>>>(emb_t, ws + OFF_ENT, 2048);
    emb_norm_kernel<<<8, TPB, 0, stream>>>(emb_b, ws + OFF_ENB, 2048);
    conv3_kernel<64, false><<<dim3(16, 4, 8), 256, 0, stream>>>(
        ws + OFF_H2, eb_c3w, eb_c3b, ws + OFF_ENCB, 128, 128, 0);
    for (int i = 0; i < 2; ++i) {
        conv3_kernel<64, true><<<dim3(16, 2, 8), 256, 0, stream>>>(
            ws + OFF_ENCB, eb_rw1 + (size_t)i * 64 * 64 * 9, nullptr, ws + OFF_RH, 128, 64, 0);
        if (i == 1)
            conv1_kernel<true, true, true><<<dim3(16, 4, 8), 256, 0, stream>>>(
                ws + OFF_RH, eb_rw2 + (size_t)i * 128 * 32, nullptr, ws + OFF_ENCB, 64, 128, 4096);
        else
            conv1_kernel<true, true, false><<<dim3(16, 4, 8), 256, 0, stream>>>(
                ws + OFF_RH, eb_rw2 + (size_t)i * 128 * 32, nullptr, ws + OFF_ENCB, 64, 128, 4096);
    }

    // ===== EncoderTop =====
    conv4s2_kernel<32><<<dim3(4, 4, 8), 256, 0, stream>>>(
        ws + OFF_ENCB, et_c1w, et_c1b, ws + OFF_T1, 128, 128, 1);
    conv3_kernel<32, false><<<dim3(4, 4, 8), 256, 0, stream>>>(
        ws + OFF_T1, et_c2w, et_c2b, ws + OFF_T2, 128, 128, 1);
    for (int i = 0; i < 2; ++i) {
        conv3_kernel<32, true><<<dim3(4, 2, 8), 256, 0, stream>>>(
            ws + OFF_T2, et_rw1 + (size_t)i * 64 * 64 * 9, nullptr, ws + OFF_RH, 128, 64, 0);
        if (i == 1)
            conv1_kernel<true, true, true><<<dim3(4, 4, 8), 256, 0, stream>>>(
                ws + OFF_RH, et_rw2 + (size_t)i * 128 * 32, nullptr, ws + OFF_T2, 64, 128, 1024);
        else
            conv1_kernel<true, true, false><<<dim3(4, 4, 8), 256, 0, stream>>>(
                ws + OFF_RH, et_rw2 + (size_t)i * 128 * 32, nullptr, ws + OFF_T2, 64, 128, 1024);
    }

    // ===== top VQ =====
    conv1_kernel<false, false, false><<<dim3(4, 4, 8), 256, 0, stream>>>(
        ws + OFF_T2, pvt_w, pvt_b, ws + OFF_ZT, 128, 128, 1024);
    vq_kernel<<<128, 256, 0, stream>>>(ws + OFF_ZT, emb_t, ws + OFF_ENT, o_qt, ws + OFF_LPT, 1024, 2048);
    loss_finish_kernel<<<1, 256, 0, stream>>>(ws + OFF_LPT, 128, 0.25f / (8192.0f * 128.0f), o_loss_t);

    // up_t = conv_t(q_t) -> (8,128,64,64)
    convt4_kernel<64, 4, 32><<<dim3(16, 4, 8), 256, 0, stream>>>(
        o_qt, up_w, up_b, ws + OFF_UPT, 128, 128, 0);

    // ===== PreVQBot / bottom VQ =====
    {
        const long long nel = 8LL * 256 * 4096;
        regroup_kernel<<<(unsigned)((nel + TPB - 1) / TPB), TPB, 0, stream>>>(
            ws + OFF_ENCB, ws + OFF_UPT, ws + OFF_JOIN, 4096);
    }
    conv1_kernel<false, false, false><<<dim3(16, 4, 8), 256, 0, stream>>>(
        ws + OFF_JOIN, pvb_w, pvb_b, ws + OFF_ZB, 256, 128, 4096);
    vq_kernel<<<512, 256, 0, stream>>>(ws + OFF_ZB, emb_b, ws + OFF_ENB, o_qb, ws + OFF_LPB, 4096, 2048);
    loss_finish_kernel<<<1, 256, 0, stream>>>(ws + OFF_LPB, 512, 0.25f / (32768.0f * 128.0f), o_loss_b);

    // ===== DecoderBot =====
    {
        const long long nel = 8LL * 256 * 4096;
        regroup_kernel<<<(unsigned)((nel + TPB - 1) / TPB), TPB, 0, stream>>>(
            ws + OFF_UPT, o_qb, ws + OFF_DJ, 4096);
    }
    conv3_kernel<64, false><<<dim3(16, 4, 8), 256, 0, stream>>>(
        ws + OFF_DJ, db_c1w, db_c1b, ws + OFF_Y, 256, 128, 0);
    for (int i = 0; i < 2; ++i) {
        conv3_kernel<64, true><<<dim3(16, 2, 8), 256, 0, stream>>>(
            ws + OFF_Y, db_rw1 + (size_t)i * 64 * 64 * 9, nullptr, ws + OFF_RH, 128, 64, 0);
        if (i == 1)
            conv1_kernel<true, true, true><<<dim3(16, 4, 8), 256, 0, stream>>>(
                ws + OFF_RH, db_rw2 + (size_t)i * 128 * 32, nullptr, ws + OFF_Y, 64, 128, 4096);
        else
            conv1_kernel<true, true, false><<<dim3(16, 4, 8), 256, 0, stream>>>(
                ws + OFF_RH, db_rw2 + (size_t)i * 128 * 32, nullptr, ws + OFF_Y, 64, 128, 4096);
    }
    convt4_kernel<128, 2, 32><<<dim3(64, 2, 8), 256, 0, stream>>>(
        ws + OFF_Y, db_t1w, db_t1b, ws + OFF_Y1, 128, 64, 1);
    convt4_kernel<256, 2, 16><<<dim3(128, 2, 8), 128, 0, stream>>>(
        ws + OFF_Y1, db_t2w, db_t2b, ws + OFF_Y2, 64, 32, 0);
    {
        const long long nel = 8LL * 4 * 65536;
        outconv_kernel<<<(unsigned)((nel + TPB - 1) / TPB), TPB, 0, stream>>>(
            ws + OFF_Y2, db_odw, db_odb, db_orw, db_orb, o_recon);
    }
}

// Round 4
// 1799.461 us; speedup vs baseline: 6.0050x; 1.6359x over previous
//
#include <hip/hip_runtime.h>
#include <cstddef>

#define TPB 256

__device__ __forceinline__ float4 relu4(float4 v) {
    v.x = fmaxf(v.x, 0.0f); v.y = fmaxf(v.y, 0.0f);
    v.z = fmaxf(v.z, 0.0f); v.w = fmaxf(v.w, 0.0f);
    return v;
}

// Split-source channel picker for the regrouped concat layers:
// joined ch (g*128 + l), l in [0,128): l<64 -> a[n][g*64+l], else b[n][g*64+l-64]
__device__ __forceinline__ const float* pick_src(const float* a, const float* b,
                                                 int n, int g, int l, int HW) {
    return (l < 64) ? a + ((size_t)n * 128 + g * 64 + l) * HW
                    : b + ((size_t)n * 128 + g * 64 + (l - 64)) * HW;
}

// ===========================================================================
// 3x3 s1 p1 grouped conv (groups=2). Tile: 32 oc x (ROWS*W) px. 256 thr.
// Full-width tiles: halo cols are always zero-pad. float4 staging.
// ===========================================================================
template<int W, int ROWS, bool RELU_IN, bool SPLIT>
__global__ __launch_bounds__(256) void conv3_kernel(
    const float* __restrict__ in, const float* __restrict__ in2,
    const float* __restrict__ wgt, const float* __restrict__ bias,
    float* __restrict__ out, int Cin, int Cout, int relu_out)
{
    constexpr int J = ROWS * W / 64;
    constexpr int ICB = 8;
    constexpr int IN_H = ROWS + 2, IN_W2 = W + 8;
    constexpr int W4 = W / 4;
    __shared__ float s_in[ICB][IN_H][IN_W2];
    __shared__ float s_w[ICB * 9 * 32];

    const int tid = threadIdx.x;
    const int tx = tid & 63, ty = tid >> 6;
    const int n = blockIdx.z, oc0 = blockIdx.y * 32, r0 = blockIdx.x * ROWS;
    const int icg = Cin >> 1, ocg = Cout >> 1;
    const int g = oc0 / ocg;

    float acc[8][J];
    #pragma unroll
    for (int o = 0; o < 8; ++o) {
        const float b = bias ? bias[oc0 + ty * 8 + o] : 0.0f;
        #pragma unroll
        for (int j = 0; j < J; ++j) acc[o][j] = b;
    }

    const float* inb = SPLIT ? nullptr
                             : in + ((size_t)n * Cin + (size_t)g * icg) * (W * W);

    for (int ic0 = 0; ic0 < icg; ic0 += ICB) {
        __syncthreads();
        for (int i = tid; i < ICB * IN_H * W4; i += 256) {
            const int icl = i / (IN_H * W4);
            const int rem = i - icl * (IN_H * W4);
            const int rr = rem / W4, c4 = rem - rr * W4;
            const int y = r0 - 1 + rr;
            float4 v = make_float4(0.f, 0.f, 0.f, 0.f);
            if ((unsigned)y < (unsigned)W) {
                const float* src = SPLIT ? pick_src(in, in2, n, g, ic0 + icl, W * W)
                                         : inb + (size_t)(ic0 + icl) * (W * W);
                v = *(const float4*)(src + (size_t)y * W + 4 * c4);
            }
            if (RELU_IN) v = relu4(v);
            *(float4*)&s_in[icl][rr][4 + 4 * c4] = v;
        }
        for (int i = tid; i < ICB * IN_H; i += 256) {
            const int icl = i / IN_H, rr = i - icl * IN_H;
            s_in[icl][rr][3] = 0.0f;
            s_in[icl][rr][W + 4] = 0.0f;
        }
        for (int i = tid; i < ICB * 9 * 32; i += 256) {
            const int ocl = i & 31, rest = i >> 5;
            const int k = rest % 9, icl = rest / 9;
            s_w[i] = wgt[((size_t)(oc0 + ocl) * icg + (ic0 + icl)) * 9 + k];
        }
        __syncthreads();

        #pragma unroll 1
        for (int icl = 0; icl < ICB; ++icl) {
            const float* swb = s_w + icl * 288 + ty * 8;
            #pragma unroll
            for (int ky = 0; ky < 3; ++ky) {
                #pragma unroll
                for (int kx = 0; kx < 3; ++kx) {
                    const int kq = ky * 3 + kx;
                    const float4 wA = *(const float4*)(swb + kq * 32);
                    const float4 wB = *(const float4*)(swb + kq * 32 + 4);
                    #pragma unroll
                    for (int j = 0; j < J; ++j) {
                        const int p = j * 64 + tx;
                        const int rr = p / W, cc = p - rr * W;
                        const float v = s_in[icl][rr + ky][cc + 3 + kx];
                        acc[0][j] = fmaf(wA.x, v, acc[0][j]);
                        acc[1][j] = fmaf(wA.y, v, acc[1][j]);
                        acc[2][j] = fmaf(wA.z, v, acc[2][j]);
                        acc[3][j] = fmaf(wA.w, v, acc[3][j]);
                        acc[4][j] = fmaf(wB.x, v, acc[4][j]);
                        acc[5][j] = fmaf(wB.y, v, acc[5][j]);
                        acc[6][j] = fmaf(wB.z, v, acc[6][j]);
                        acc[7][j] = fmaf(wB.w, v, acc[7][j]);
                    }
                }
            }
        }
    }

    const int HWo = W * W;
    float* ob = out + ((size_t)n * Cout + oc0 + ty * 8) * HWo;
    #pragma unroll
    for (int o = 0; o < 8; ++o) {
        #pragma unroll
        for (int j = 0; j < J; ++j) {
            const int p = j * 64 + tx;
            const int rr = p / W, cc = p - rr * W;
            float r = acc[o][j];
            if (relu_out) r = fmaxf(r, 0.0f);
            ob[(size_t)o * HWo + (size_t)(r0 + rr) * W + cc] = r;
        }
    }
}

// ===========================================================================
// 4x4 s2 p1 grouped conv (groups=2). W = OUTPUT width; input 2W x 2W.
// ===========================================================================
template<int W, int ROWS>
__global__ __launch_bounds__(256) void conv4s2_kernel(
    const float* __restrict__ in, const float* __restrict__ wgt,
    const float* __restrict__ bias, float* __restrict__ out,
    int Cin, int Cout, int relu_out)
{
    constexpr int J = ROWS * W / 64;
    constexpr int ICB = 4;
    constexpr int IN_H = 2 * ROWS + 2, IN_W2 = 2 * W + 8;
    constexpr int W24 = W / 2;             // float4 per input row
    __shared__ float s_in[ICB][IN_H][IN_W2];
    __shared__ float s_w[ICB * 16 * 32];

    const int tid = threadIdx.x;
    const int tx = tid & 63, ty = tid >> 6;
    const int n = blockIdx.z, oc0 = blockIdx.y * 32, r0 = blockIdx.x * ROWS;
    const int icg = Cin >> 1, ocg = Cout >> 1;
    const int g = oc0 / ocg;
    const int Hin = 2 * W;

    float acc[8][J];
    #pragma unroll
    for (int o = 0; o < 8; ++o) {
        const float b = bias ? bias[oc0 + ty * 8 + o] : 0.0f;
        #pragma unroll
        for (int j = 0; j < J; ++j) acc[o][j] = b;
    }

    const float* inb = in + ((size_t)n * Cin + (size_t)g * icg) * (Hin * Hin);
    for (int ic0 = 0; ic0 < icg; ic0 += ICB) {
        __syncthreads();
        for (int i = tid; i < ICB * IN_H * W24; i += 256) {
            const int icl = i / (IN_H * W24);
            const int rem = i - icl * (IN_H * W24);
            const int rr = rem / W24, c4 = rem - rr * W24;
            const int y = 2 * r0 - 1 + rr;
            float4 v = make_float4(0.f, 0.f, 0.f, 0.f);
            if ((unsigned)y < (unsigned)Hin)
                v = *(const float4*)(inb + (size_t)(ic0 + icl) * (Hin * Hin)
                                     + (size_t)y * Hin + 4 * c4);
            *(float4*)&s_in[icl][rr][4 + 4 * c4] = v;
        }
        for (int i = tid; i < ICB * IN_H; i += 256) {
            const int icl = i / IN_H, rr = i - icl * IN_H;
            s_in[icl][rr][3] = 0.0f;
            s_in[icl][rr][2 * W + 4] = 0.0f;
        }
        for (int i = tid; i < ICB * 16 * 32; i += 256) {
            const int ocl = i & 31, rest = i >> 5;
            const int k = rest & 15, icl = rest >> 4;
            s_w[i] = wgt[((size_t)(oc0 + ocl) * icg + (ic0 + icl)) * 16 + k];
        }
        __syncthreads();

        #pragma unroll 1
        for (int icl = 0; icl < ICB; ++icl) {
            const float* swb = s_w + icl * 512 + ty * 8;
            #pragma unroll
            for (int ky = 0; ky < 4; ++ky) {
                #pragma unroll
                for (int kx = 0; kx < 4; ++kx) {
                    const int kq = ky * 4 + kx;
                    const float4 wA = *(const float4*)(swb + kq * 32);
                    const float4 wB = *(const float4*)(swb + kq * 32 + 4);
                    #pragma unroll
                    for (int j = 0; j < J; ++j) {
                        const int p = j * 64 + tx;
                        const int rr = p / W, cc = p - rr * W;
                        const float v = s_in[icl][2 * rr + ky][2 * cc + 3 + kx];
                        acc[0][j] = fmaf(wA.x, v, acc[0][j]);
                        acc[1][j] = fmaf(wA.y, v, acc[1][j]);
                        acc[2][j] = fmaf(wA.z, v, acc[2][j]);
                        acc[3][j] = fmaf(wA.w, v, acc[3][j]);
                        acc[4][j] = fmaf(wB.x, v, acc[4][j]);
                        acc[5][j] = fmaf(wB.y, v, acc[5][j]);
                        acc[6][j] = fmaf(wB.z, v, acc[6][j]);
                        acc[7][j] = fmaf(wB.w, v, acc[7][j]);
                    }
                }
            }
        }
    }

    const int HWo = W * W;
    float* ob = out + ((size_t)n * Cout + oc0 + ty * 8) * HWo;
    #pragma unroll
    for (int o = 0; o < 8; ++o) {
        #pragma unroll
        for (int j = 0; j < J; ++j) {
            const int p = j * 64 + tx;
            const int rr = p / W, cc = p - rr * W;
            float r = acc[o][j];
            if (relu_out) r = fmaxf(r, 0.0f);
            ob[(size_t)o * HWo + (size_t)(r0 + rr) * W + cc] = r;
        }
    }
}

// ===========================================================================
// 1x1 grouped conv (pixel GEMM). Tile: 32 oc x 128 px.
// ===========================================================================
template<bool RELU_IN, bool ACC, bool RELU_OUT, bool SPLIT>
__global__ __launch_bounds__(256) void conv1_kernel(
    const float* __restrict__ in, const float* __restrict__ in2,
    const float* __restrict__ wgt, const float* __restrict__ bias,
    float* __restrict__ out, int Cin, int Cout, int HW)
{
    constexpr int ICB = 16;
    __shared__ float s_in[ICB][128];
    __shared__ float s_w[ICB * 32];

    const int tid = threadIdx.x;
    const int tx = tid & 63, ty = tid >> 6;
    const int n = blockIdx.z, oc0 = blockIdx.y * 32, p0 = blockIdx.x * 128;
    const int icg = Cin >> 1, ocg = Cout >> 1;
    const int g = oc0 / ocg;

    float acc[8][2];
    #pragma unroll
    for (int o = 0; o < 8; ++o) {
        const float b = bias ? bias[oc0 + ty * 8 + o] : 0.0f;
        acc[o][0] = b; acc[o][1] = b;
    }

    const float* inb = SPLIT ? nullptr
                             : in + ((size_t)n * Cin + (size_t)g * icg) * HW + p0;
    for (int ic0 = 0; ic0 < icg; ic0 += ICB) {
        __syncthreads();
        for (int i = tid; i < ICB * 32; i += 256) {
            const int icl = i >> 5, c4 = i & 31;
            const float* src = SPLIT ? pick_src(in, in2, n, g, ic0 + icl, HW) + p0
                                     : inb + (size_t)(ic0 + icl) * HW;
            float4 v = *(const float4*)(src + 4 * c4);
            if (RELU_IN) v = relu4(v);
            *(float4*)&s_in[icl][4 * c4] = v;
        }
        for (int i = tid; i < ICB * 32; i += 256) {
            const int ocl = i & 31, icl = i >> 5;
            s_w[i] = wgt[(size_t)(oc0 + ocl) * icg + ic0 + icl];
        }
        __syncthreads();

        #pragma unroll 4
        for (int icl = 0; icl < ICB; ++icl) {
            const float4 wA = *(const float4*)(s_w + icl * 32 + ty * 8);
            const float4 wB = *(const float4*)(s_w + icl * 32 + ty * 8 + 4);
            #pragma unroll
            for (int j = 0; j < 2; ++j) {
                const float v = s_in[icl][j * 64 + tx];
                acc[0][j] = fmaf(wA.x, v, acc[0][j]);
                acc[1][j] = fmaf(wA.y, v, acc[1][j]);
                acc[2][j] = fmaf(wA.z, v, acc[2][j]);
                acc[3][j] = fmaf(wA.w, v, acc[3][j]);
                acc[4][j] = fmaf(wB.x, v, acc[4][j]);
                acc[5][j] = fmaf(wB.y, v, acc[5][j]);
                acc[6][j] = fmaf(wB.z, v, acc[6][j]);
                acc[7][j] = fmaf(wB.w, v, acc[7][j]);
            }
        }
    }

    float* ob = out + ((size_t)n * Cout + oc0 + ty * 8) * HW + p0;
    #pragma unroll
    for (int o = 0; o < 8; ++o) {
        #pragma unroll
        for (int j = 0; j < 2; ++j) {
            const size_t idx = (size_t)o * HW + j * 64 + tx;
            float r = acc[o][j];
            if (ACC) r += ob[idx];
            if (RELU_OUT) r = fmaxf(r, 0.0f);
            ob[idx] = r;
        }
    }
}

// ===========================================================================
// Grouped ConvTranspose2d K4 s2 p1 (groups=2). W = OUTPUT width; input W/2.
// torch layout w: (Cin, Cout/groups, 4, 4). Parity-decomposed taps.
// ===========================================================================
template<int W, int ROWS, int OCT>
__global__ __launch_bounds__(64 * (OCT / 8)) void convt4_kernel(
    const float* __restrict__ in, const float* __restrict__ wgt,
    const float* __restrict__ bias, float* __restrict__ out,
    int Cin, int Cout, int relu_out)
{
    constexpr int NTHR = 64 * (OCT / 8);
    constexpr int PXT  = ROWS * W / 64;
    constexpr int WP   = W / 64;
    constexpr int ICB  = 8;
    constexpr int RIN  = ((ROWS + 1) >> 1) + 2;
    constexpr int CIN  = W / 2 + 2;
    __shared__ float s_in[ICB][RIN][CIN];
    __shared__ float s_w[ICB * 16 * OCT];

    const int tid = threadIdx.x;
    const int tx = tid & 63, ty = tid >> 6;
    const int n = blockIdx.z;
    const int oc0 = blockIdx.y * OCT;
    const int r0 = blockIdx.x * ROWS;       // even
    const int icg = Cin >> 1, ocg = Cout >> 1;
    const int g = oc0 / ocg, of0 = oc0 - g * ocg;
    const int Hin = W / 2;
    const int iy_lo = (r0 - 2) >> 1;

    float acc[8][PXT];
    #pragma unroll
    for (int o = 0; o < 8; ++o) {
        const float b = bias ? bias[oc0 + ty * 8 + o] : 0.0f;
        #pragma unroll
        for (int j = 0; j < PXT; ++j) acc[o][j] = b;
    }

    const float* inb = in + ((size_t)n * Cin + (size_t)g * icg) * (Hin * Hin);
    const int kxl = ((tx + 1) & 1);
    const int hx  = (tx + 1) >> 1;

    for (int ic0 = 0; ic0 < icg; ic0 += ICB) {
        __syncthreads();
        for (int i = tid; i < ICB * RIN * CIN; i += NTHR) {
            const int icl = i / (RIN * CIN);
            const int rem = i - icl * (RIN * CIN);
            const int rr = rem / CIN, cc = rem - rr * CIN;
            const int y = iy_lo + rr, x = cc - 1;
            float v = 0.0f;
            if ((unsigned)y < (unsigned)Hin && (unsigned)x < (unsigned)Hin)
                v = inb[(size_t)(ic0 + icl) * (Hin * Hin) + y * Hin + x];
            s_in[icl][rr][cc] = v;
        }
        for (int i = tid; i < ICB * 16 * OCT; i += NTHR) {
            const int ocl = i & (OCT - 1);
            const int rest = i / OCT;
            const int k = rest & 15, icl = rest >> 4;
            s_w[i] = wgt[((size_t)(g * icg + ic0 + icl) * ocg + of0 + ocl) * 16 + k];
        }
        __syncthreads();

        #pragma unroll 1
        for (int icl = 0; icl < ICB; ++icl) {
            const float* swb = s_w + icl * 16 * OCT + ty * 8;
            #pragma unroll
            for (int tt = 0; tt < 4; ++tt) {
                const int ty2 = tt >> 1, tx2 = tt & 1;
                float4 wp0[2], wp1[2];
                #pragma unroll
                for (int par = 0; par < 2; ++par) {
                    const int koff = ((2 * ty2 + par) * 4 + (kxl + 2 * tx2)) * OCT;
                    wp0[par] = *(const float4*)(swb + koff);
                    wp1[par] = *(const float4*)(swb + koff + 4);
                }
                const int cbase = hx - tx2 + 1;
                #pragma unroll
                for (int j = 0; j < PXT; ++j) {
                    const int row_j = j / WP, m_j = j - row_j * WP;
                    const int pj = (row_j + 1) & 1;
                    const int rloc = (row_j + 1 - pj) / 2 - ty2 + 1;
                    const float v = s_in[icl][rloc][32 * m_j + cbase];
                    const float4 wa = pj ? wp0[1] : wp0[0];
                    const float4 wb = pj ? wp1[1] : wp1[0];
                    acc[0][j] = fmaf(wa.x, v, acc[0][j]);
                    acc[1][j] = fmaf(wa.y, v, acc[1][j]);
                    acc[2][j] = fmaf(wa.z, v, acc[2][j]);
                    acc[3][j] = fmaf(wa.w, v, acc[3][j]);
                    acc[4][j] = fmaf(wb.x, v, acc[4][j]);
                    acc[5][j] = fmaf(wb.y, v, acc[5][j]);
                    acc[6][j] = fmaf(wb.z, v, acc[6][j]);
                    acc[7][j] = fmaf(wb.w, v, acc[7][j]);
                }
            }
        }
    }

    const int HWo = W * W;
    float* ob = out + ((size_t)n * Cout + oc0 + ty * 8) * HWo;
    #pragma unroll
    for (int o = 0; o < 8; ++o) {
        #pragma unroll
        for (int j = 0; j < PXT; ++j) {
            const int row_j = j / WP, m_j = j - row_j * WP;
            float r = acc[o][j];
            if (relu_out) r = fmaxf(r, 0.0f);
            ob[(size_t)o * HWo + (size_t)(r0 + row_j) * W + 64 * m_j + tx] = r;
        }
    }
}

// ===========================================================================
// Fused encoder head (float4): relu(concat(1x1 depth, 1x1 rgb))
// ===========================================================================
__global__ void head_kernel(const float* __restrict__ x,
                            const float* __restrict__ dw, const float* __restrict__ db,
                            const float* __restrict__ rw, const float* __restrict__ rb,
                            float* __restrict__ out)
{
    const int idx = blockIdx.x * TPB + threadIdx.x;       // f4 index
    const int HW4 = 16384;
    if (idx >= 8 * 64 * HW4) return;
    const int p4 = idx & (HW4 - 1);
    const int t = idx >> 14;
    const int c = t & 63, n = t >> 6;
    const float4* xb4 = (const float4*)(x + (size_t)n * 4 * 65536);
    float4 v;
    if (c < 32) {
        const float w = dw[c], b = db[c];
        const float4 d = xb4[p4];
        v.x = fmaf(d.x, w, b); v.y = fmaf(d.y, w, b);
        v.z = fmaf(d.z, w, b); v.w = fmaf(d.w, w, b);
    } else {
        const int cc = c - 32;
        const float w0 = rw[cc * 3], w1 = rw[cc * 3 + 1], w2 = rw[cc * 3 + 2];
        const float b = rb[cc];
        const float4 r = xb4[HW4 + p4], g4 = xb4[2 * HW4 + p4], bl = xb4[3 * HW4 + p4];
        v.x = fmaf(bl.x, w2, fmaf(g4.x, w1, fmaf(r.x, w0, b)));
        v.y = fmaf(bl.y, w2, fmaf(g4.y, w1, fmaf(r.y, w0, b)));
        v.z = fmaf(bl.z, w2, fmaf(g4.z, w1, fmaf(r.z, w0, b)));
        v.w = fmaf(bl.w, w2, fmaf(g4.w, w1, fmaf(r.w, w0, b)));
    }
    ((float4*)out)[idx] = relu4(v);
}

// Precompute |emb_k|^2
__global__ void emb_norm_kernel(const float* __restrict__ emb, float* __restrict__ en, int K)
{
    const int k = blockIdx.x * TPB + threadIdx.x;
    if (k >= K) return;
    const float4* e = (const float4*)(emb + (size_t)k * 128);
    float s = 0.0f;
    for (int c = 0; c < 32; ++c) {
        const float4 t = e[c];
        s = fmaf(t.x, t.x, s); s = fmaf(t.y, t.y, s);
        s = fmaf(t.z, t.z, s); s = fmaf(t.w, t.w, s);
    }
    en[k] = s;
}

// ===========================================================================
// VQ: 64 z-vectors per block; register tile 4v x 4e; float4 c-chunks in LDS.
// Thread (vg,eg): v in {4vg..4vg+3}, e in {eg, eg+16, eg+32, eg+48} (strided).
// ===========================================================================
#define VQ_TV 64
#define VQ_TE 64
__global__ __launch_bounds__(256) void vq_kernel(
    const float* __restrict__ z, const float* __restrict__ emb,
    const float* __restrict__ en_g,
    float* __restrict__ q, float* __restrict__ lossp,
    int HW, int Kc)
{
    __shared__ float zs[32][65][4];
    __shared__ float es[32][65][4];
    __shared__ float en[VQ_TE];
    __shared__ float rdd[VQ_TV][16];
    __shared__ int   rdi[VQ_TV][16];
    __shared__ int   idxv[VQ_TV];
    __shared__ float red[256];

    const int tid = threadIdx.x;
    const int vg = tid >> 4, eg = tid & 15;
    const long long gv0 = (long long)blockIdx.x * VQ_TV;
    const int n = (int)(gv0 / HW);
    const int p0 = (int)(gv0 - (long long)n * HW);
    const float* zb = z + (size_t)n * 128 * HW + p0;

    for (int i = tid; i < 64 * 128; i += 256) {
        const int v = i & 63, c = i >> 6;
        zs[c >> 2][v][c & 3] = zb[(size_t)c * HW + v];
    }
    __syncthreads();

    float best[4]; int bidx[4];
    #pragma unroll
    for (int r = 0; r < 4; ++r) { best[r] = 1e30f; bidx[r] = 0; }

    for (int e0 = 0; e0 < Kc; e0 += VQ_TE) {
        for (int i = tid; i < VQ_TE * 128; i += 256) {
            const int c = i & 127, el = i >> 7;
            es[c >> 2][el][c & 3] = emb[(size_t)(e0 + el) * 128 + c];
        }
        if (tid < VQ_TE) en[tid] = en_g[e0 + tid];
        __syncthreads();

        float dot[4][4];
        #pragma unroll
        for (int r = 0; r < 4; ++r)
            #pragma unroll
            for (int s = 0; s < 4; ++s) dot[r][s] = 0.0f;

        for (int c4 = 0; c4 < 32; ++c4) {
            float4 zr[4], ee[4];
            #pragma unroll
            for (int r = 0; r < 4; ++r) zr[r] = *(const float4*)&zs[c4][4 * vg + r][0];
            #pragma unroll
            for (int s = 0; s < 4; ++s) ee[s] = *(const float4*)&es[c4][eg + 16 * s][0];
            #pragma unroll
            for (int r = 0; r < 4; ++r) {
                #pragma unroll
                for (int s = 0; s < 4; ++s) {
                    dot[r][s] = fmaf(zr[r].x, ee[s].x, dot[r][s]);
                    dot[r][s] = fmaf(zr[r].y, ee[s].y, dot[r][s]);
                    dot[r][s] = fmaf(zr[r].z, ee[s].z, dot[r][s]);
                    dot[r][s] = fmaf(zr[r].w, ee[s].w, dot[r][s]);
                }
            }
        }
        #pragma unroll
        for (int s = 0; s < 4; ++s) {
            const float e2 = en[eg + 16 * s];
            const int ei = e0 + eg + 16 * s;
            #pragma unroll
            for (int r = 0; r < 4; ++r) {
                const float d = e2 - 2.0f * dot[r][s];
                if (d < best[r]) { best[r] = d; bidx[r] = ei; }
            }
        }
        __syncthreads();
    }

    #pragma unroll
    for (int r = 0; r < 4; ++r) { rdd[4 * vg + r][eg] = best[r]; rdi[4 * vg + r][eg] = bidx[r]; }
    __syncthreads();
    if (tid < VQ_TV) {
        float bd = rdd[tid][0]; int bi = rdi[tid][0];
        for (int j = 1; j < 16; ++j) {
            const float d = rdd[tid][j]; const int i2 = rdi[tid][j];
            if (d < bd || (d == bd && i2 < bi)) { bd = d; bi = i2; }
        }
        idxv[tid] = bi;
    }
    __syncthreads();

    float ls = 0.0f;
    float* qb = q + (size_t)n * 128 * HW + p0;
    for (int i = tid; i < 64 * 128; i += 256) {
        const int v = i & 63, c = i >> 6;
        const float e = emb[(size_t)idxv[v] * 128 + c];
        qb[(size_t)c * HW + v] = e;
        const float diff = e - zs[c >> 2][v][c & 3];
        ls = fmaf(diff, diff, ls);
    }
    red[tid] = ls;
    __syncthreads();
    for (int s = 128; s > 0; s >>= 1) {
        if (tid < s) red[tid] += red[tid + s];
        __syncthreads();
    }
    if (tid == 0) lossp[blockIdx.x] = red[0];
}

__global__ void loss_finish_kernel(const float* __restrict__ p, int n, float scale,
                                   float* __restrict__ out)
{
    __shared__ float red[256];
    float s = 0.0f;
    for (int i = threadIdx.x; i < n; i += 256) s += p[i];
    red[threadIdx.x] = s;
    __syncthreads();
    for (int k = 128; k > 0; k >>= 1) {
        if (threadIdx.x < k) red[threadIdx.x] += red[threadIdx.x + k];
        __syncthreads();
    }
    if (threadIdx.x == 0) out[0] = red[0] * scale;
}

// Final 1x1 heads (float4): y2 (8,32,256,256) -> recon (8,4,256,256)
__global__ void outconv_kernel(const float* __restrict__ y,
                               const float* __restrict__ odw, const float* __restrict__ odb,
                               const float* __restrict__ orw, const float* __restrict__ orb,
                               float* __restrict__ out)
{
    const int idx = blockIdx.x * TPB + threadIdx.x;      // f4 index
    const int HW4 = 16384;
    if (idx >= 8 * 4 * HW4) return;
    const int p4 = idx & (HW4 - 1);
    const int t = idx >> 14;
    const int c = t & 3, n = t >> 2;
    const float4* yb4 = (const float4*)(y + (size_t)n * 32 * 65536);
    float4 v;
    const int base = (c == 0) ? 0 : 16;
    const float* wv = (c == 0) ? odw : orw + (c - 1) * 16;
    const float b = (c == 0) ? odb[0] : orb[c - 1];
    v.x = b; v.y = b; v.z = b; v.w = b;
    for (int k = 0; k < 16; ++k) {
        const float w = wv[k];
        const float4 f = yb4[(size_t)(base + k) * HW4 + p4];
        v.x = fmaf(f.x, w, v.x); v.y = fmaf(f.y, w, v.y);
        v.z = fmaf(f.z, w, v.z); v.w = fmaf(f.w, w, v.w);
    }
    ((float4*)out)[idx] = v;
}

extern "C" void kernel_launch(void* const* d_in, const int* in_sizes, int n_in,
                              void* d_out, int out_size, void* d_ws, size_t ws_size,
                              hipStream_t stream)
{
    const float* x      = (const float*)d_in[0];
    const float* eb_dw  = (const float*)d_in[1];
    const float* eb_db  = (const float*)d_in[2];
    const float* eb_rw  = (const float*)d_in[3];
    const float* eb_rb  = (const float*)d_in[4];
    const float* eb_c1w = (const float*)d_in[5];
    const float* eb_c1b = (const float*)d_in[6];
    const float* eb_c2w = (const float*)d_in[7];
    const float* eb_c2b = (const float*)d_in[8];
    const float* eb_c3w = (const float*)d_in[9];
    const float* eb_c3b = (const float*)d_in[10];
    const float* eb_rw1 = (const float*)d_in[11];
    const float* eb_rw2 = (const float*)d_in[12];
    const float* et_c1w = (const float*)d_in[13];
    const float* et_c1b = (const float*)d_in[14];
    const float* et_c2w = (const float*)d_in[15];
    const float* et_c2b = (const float*)d_in[16];
    const float* et_rw1 = (const float*)d_in[17];
    const float* et_rw2 = (const float*)d_in[18];
    const float* pvt_w  = (const float*)d_in[19];
    const float* pvt_b  = (const float*)d_in[20];
    const float* up_w   = (const float*)d_in[21];
    const float* up_b   = (const float*)d_in[22];
    const float* pvb_w  = (const float*)d_in[23];
    const float* pvb_b  = (const float*)d_in[24];
    const float* emb_t  = (const float*)d_in[25];
    const float* emb_b  = (const float*)d_in[26];
    const float* db_c1w = (const float*)d_in[27];
    const float* db_c1b = (const float*)d_in[28];
    const float* db_rw1 = (const float*)d_in[29];
    const float* db_rw2 = (const float*)d_in[30];
    const float* db_t1w = (const float*)d_in[31];
    const float* db_t1b = (const float*)d_in[32];
    const float* db_t2w = (const float*)d_in[33];
    const float* db_t2b = (const float*)d_in[34];
    const float* db_odw = (const float*)d_in[35];
    const float* db_odb = (const float*)d_in[36];
    const float* db_orw = (const float*)d_in[37];
    const float* db_orb = (const float*)d_in[38];

    float* ws  = (float*)d_ws;
    float* out = (float*)d_out;

    // ---- workspace arena (float offsets). Disjointness proof per producer:
    //  H0  [0,        33554432)  head -> eb_c1
    //  H1  [33554432, 41943040)  eb_c1 -> eb_c2
    //  H2  [0,         4194304)  eb_c2 -> eb_c3        (H0 dead)
    //  ENCB[4194304,   8388608)  eb_c3 -> pvb conv1
    //  RH  [8388608,  10485760)  res-stack temp (all stacks)
    //  T1  [10485760, 11534336)  et_c1 -> et_c2
    //  T2  [11534336, 12582912)  et_c2 -> pvt conv
    //  ZT  [12582912, 13631488)  pvt -> vq_t
    //  UPT [13631488, 17825792)  convt up -> db_c1
    //  ZB  [17825792, 22020096)  pvb -> vq_b
    //  Y   [22020096, 26214400)  db_c1 -> db_t1        (ZB dead)
    //  Y1  [26214400, 34603008)  db_t1 -> db_t2
    //  Y2  [0,        16777216)  db_t2 -> outconv      (H2/ENCB/RH/T1/T2/ZT/UPT dead)
    //  ENT [34603008, 34605056)  emb_norm -> vq_t      (H1 dead by then)
    //  ENB [34605056, 34607104)  emb_norm -> vq_b
    //  LPT [34607104, 34607232)
    //  LPB [34607232, 34607744)
    const size_t OFF_H0   = 0;
    const size_t OFF_H1   = 33554432;
    const size_t OFF_H2   = 0;
    const size_t OFF_ENCB = 4194304;
    const size_t OFF_RH   = 8388608;
    const size_t OFF_T1   = 10485760;
    const size_t OFF_T2   = 11534336;
    const size_t OFF_ZT   = 12582912;
    const size_t OFF_UPT  = 13631488;
    const size_t OFF_ZB   = 17825792;
    const size_t OFF_Y    = 22020096;
    const size_t OFF_Y1   = 26214400;
    const size_t OFF_Y2   = 0;
    const size_t OFF_ENT  = 34603008;
    const size_t OFF_ENB  = 34605056;
    const size_t OFF_LPT  = 34607104;
    const size_t OFF_LPB  = 34607232;
    const size_t NEED     = 41943680;
    if (ws_size < NEED * sizeof(float)) return;

    // ---- output layout: loss_b, loss_t, recon, q_t, q_b ----
    float* o_loss_b = out + 0;
    float* o_loss_t = out + 1;
    float* o_recon  = out + 2;
    float* o_qt     = out + 2 + 8 * 4 * 65536;
    float* o_qb     = o_qt + 8 * 128 * 1024;

    // ===== EncoderBot =====
    head_kernel<<<8 * 64 * 16384 / TPB, TPB, 0, stream>>>(
        x, eb_dw, eb_db, eb_rw, eb_rb, ws + OFF_H0);
    conv4s2_kernel<128, 2><<<dim3(64, 2, 8), 256, 0, stream>>>(
        ws + OFF_H0, eb_c1w, eb_c1b, ws + OFF_H1, 64, 64, 1);
    conv4s2_kernel<64, 2><<<dim3(32, 4, 8), 256, 0, stream>>>(
        ws + OFF_H1, eb_c2w, eb_c2b, ws + OFF_H2, 64, 128, 1);
    emb_norm_kernel<<<8, TPB, 0, stream>>>(emb_t, ws + OFF_ENT, 2048);
    emb_norm_kernel<<<8, TPB, 0, stream>>>(emb_b, ws + OFF_ENB, 2048);
    conv3_kernel<64, 2, false, false><<<dim3(32, 4, 8), 256, 0, stream>>>(
        ws + OFF_H2, nullptr, eb_c3w, eb_c3b, ws + OFF_ENCB, 128, 128, 0);
    for (int i = 0; i < 2; ++i) {
        conv3_kernel<64, 2, true, false><<<dim3(32, 2, 8), 256, 0, stream>>>(
            ws + OFF_ENCB, nullptr, eb_rw1 + (size_t)i * 64 * 64 * 9, nullptr,
            ws + OFF_RH, 128, 64, 0);
        if (i == 1)
            conv1_kernel<true, true, true, false><<<dim3(32, 4, 8), 256, 0, stream>>>(
                ws + OFF_RH, nullptr, eb_rw2 + (size_t)i * 128 * 32, nullptr,
                ws + OFF_ENCB, 64, 128, 4096);
        else
            conv1_kernel<true, true, false, false><<<dim3(32, 4, 8), 256, 0, stream>>>(
                ws + OFF_RH, nullptr, eb_rw2 + (size_t)i * 128 * 32, nullptr,
                ws + OFF_ENCB, 64, 128, 4096);
    }

    // ===== EncoderTop =====
    conv4s2_kernel<32, 2><<<dim3(16, 4, 8), 256, 0, stream>>>(
        ws + OFF_ENCB, et_c1w, et_c1b, ws + OFF_T1, 128, 128, 1);
    conv3_kernel<32, 2, false, false><<<dim3(16, 4, 8), 256, 0, stream>>>(
        ws + OFF_T1, nullptr, et_c2w, et_c2b, ws + OFF_T2, 128, 128, 1);
    for (int i = 0; i < 2; ++i) {
        conv3_kernel<32, 2, true, false><<<dim3(16, 2, 8), 256, 0, stream>>>(
            ws + OFF_T2, nullptr, et_rw1 + (size_t)i * 64 * 64 * 9, nullptr,
            ws + OFF_RH, 128, 64, 0);
        if (i == 1)
            conv1_kernel<true, true, true, false><<<dim3(8, 4, 8), 256, 0, stream>>>(
                ws + OFF_RH, nullptr, et_rw2 + (size_t)i * 128 * 32, nullptr,
                ws + OFF_T2, 64, 128, 1024);
        else
            conv1_kernel<true, true, false, false><<<dim3(8, 4, 8), 256, 0, stream>>>(
                ws + OFF_RH, nullptr, et_rw2 + (size_t)i * 128 * 32, nullptr,
                ws + OFF_T2, 64, 128, 1024);
    }

    // ===== top VQ =====
    conv1_kernel<false, false, false, false><<<dim3(8, 4, 8), 256, 0, stream>>>(
        ws + OFF_T2, nullptr, pvt_w, pvt_b, ws + OFF_ZT, 128, 128, 1024);
    vq_kernel<<<128, 256, 0, stream>>>(ws + OFF_ZT, emb_t, ws + OFF_ENT, o_qt,
                                       ws + OFF_LPT, 1024, 2048);
    loss_finish_kernel<<<1, 256, 0, stream>>>(ws + OFF_LPT, 128,
                                              0.25f / (8192.0f * 128.0f), o_loss_t);

    convt4_kernel<64, 2, 32><<<dim3(32, 4, 8), 256, 0, stream>>>(
        o_qt, up_w, up_b, ws + OFF_UPT, 128, 128, 0);

    // ===== PreVQBot / bottom VQ (regroup fused into conv1 staging) =====
    conv1_kernel<false, false, false, true><<<dim3(32, 4, 8), 256, 0, stream>>>(
        ws + OFF_ENCB, ws + OFF_UPT, pvb_w, pvb_b, ws + OFF_ZB, 256, 128, 4096);
    vq_kernel<<<512, 256, 0, stream>>>(ws + OFF_ZB, emb_b, ws + OFF_ENB, o_qb,
                                       ws + OFF_LPB, 4096, 2048);
    loss_finish_kernel<<<1, 256, 0, stream>>>(ws + OFF_LPB, 512,
                                              0.25f / (32768.0f * 128.0f), o_loss_b);

    // ===== DecoderBot (regroup fused into conv3 staging) =====
    conv3_kernel<64, 2, false, true><<<dim3(32, 4, 8), 256, 0, stream>>>(
        ws + OFF_UPT, o_qb, db_c1w, db_c1b, ws + OFF_Y, 256, 128, 0);
    for (int i = 0; i < 2; ++i) {
        conv3_kernel<64, 2, true, false><<<dim3(32, 2, 8), 256, 0, stream>>>(
            ws + OFF_Y, nullptr, db_rw1 + (size_t)i * 64 * 64 * 9, nullptr,
            ws + OFF_RH, 128, 64, 0);
        if (i == 1)
            conv1_kernel<true, true, true, false><<<dim3(32, 4, 8), 256, 0, stream>>>(
                ws + OFF_RH, nullptr, db_rw2 + (size_t)i * 128 * 32, nullptr,
                ws + OFF_Y, 64, 128, 4096);
        else
            conv1_kernel<true, true, false, false><<<dim3(32, 4, 8), 256, 0, stream>>>(
                ws + OFF_RH, nullptr, db_rw2 + (size_t)i * 128 * 32, nullptr,
                ws + OFF_Y, 64, 128, 4096);
    }
    convt4_kernel<128, 2, 32><<<dim3(64, 2, 8), 256, 0, stream>>>(
        ws + OFF_Y, db_t1w, db_t1b, ws + OFF_Y1, 128, 64, 1);
    convt4_kernel<256, 2, 16><<<dim3(128, 2, 8), 128, 0, stream>>>(
        ws + OFF_Y1, db_t2w, db_t2b, ws + OFF_Y2, 64, 32, 0);
    outconv_kernel<<<8 * 4 * 16384 / TPB, TPB, 0, stream>>>(
        ws + OFF_Y2, db_odw, db_odb, db_orw, db_orb, o_recon);
}

// Round 5
// 1762.187 us; speedup vs baseline: 6.1320x; 1.0212x over previous
//
#include <hip/hip_runtime.h>
#include <cstddef>

#define TPB 256

__device__ __forceinline__ float4 relu4(float4 v) {
    v.x = fmaxf(v.x, 0.0f); v.y = fmaxf(v.y, 0.0f);
    v.z = fmaxf(v.z, 0.0f); v.w = fmaxf(v.w, 0.0f);
    return v;
}

// Split-source channel picker for the regrouped concat layers:
// joined ch (g*128 + l), l in [0,128): l<64 -> a[n][g*64+l], else b[n][g*64+l-64]
__device__ __forceinline__ const float* pick_src(const float* a, const float* b,
                                                 int n, int g, int l, int HW) {
    return (l < 64) ? a + ((size_t)n * 128 + g * 64 + l) * HW
                    : b + ((size_t)n * 128 + g * 64 + (l - 64)) * HW;
}

// ===========================================================================
// 3x3 s1 p1 grouped conv (groups=2). Tile: (4*OCB) oc x (ROWS*W) px. 256 thr.
// Each thread: OCB oc x J px. Full-width tiles -> halo cols always zero-pad.
// ===========================================================================
template<int W, int ROWS, int OCB, bool RELU_IN, bool SPLIT>
__global__ __launch_bounds__(256) void conv3_kernel(
    const float* __restrict__ in, const float* __restrict__ in2,
    const float* __restrict__ wgt, const float* __restrict__ bias,
    float* __restrict__ out, int Cin, int Cout, int relu_out)
{
    constexpr int J = ROWS * W / 64;
    constexpr int OCT = OCB * 4;
    constexpr int NW = OCB / 4;
    constexpr int ICB = 8;
    constexpr int IN_H = ROWS + 2, IN_W2 = W + 8;
    constexpr int W4 = W / 4;
    __shared__ float s_in[ICB][IN_H][IN_W2];
    __shared__ float s_w[ICB * 9 * OCT];

    const int tid = threadIdx.x;
    const int tx = tid & 63, ty = tid >> 6;
    const int n = blockIdx.z, oc0 = blockIdx.y * OCT, r0 = blockIdx.x * ROWS;
    const int icg = Cin >> 1, ocg = Cout >> 1;
    const int g = oc0 / ocg;

    float acc[OCB][J];
    #pragma unroll
    for (int o = 0; o < OCB; ++o) {
        const float b = bias ? bias[oc0 + ty * OCB + o] : 0.0f;
        #pragma unroll
        for (int j = 0; j < J; ++j) acc[o][j] = b;
    }

    const float* inb = SPLIT ? nullptr
                             : in + ((size_t)n * Cin + (size_t)g * icg) * (W * W);

    for (int ic0 = 0; ic0 < icg; ic0 += ICB) {
        __syncthreads();
        for (int i = tid; i < ICB * IN_H * W4; i += 256) {
            const int icl = i / (IN_H * W4);
            const int rem = i - icl * (IN_H * W4);
            const int rr = rem / W4, c4 = rem - rr * W4;
            const int y = r0 - 1 + rr;
            float4 v = make_float4(0.f, 0.f, 0.f, 0.f);
            if ((unsigned)y < (unsigned)W) {
                const float* src = SPLIT ? pick_src(in, in2, n, g, ic0 + icl, W * W)
                                         : inb + (size_t)(ic0 + icl) * (W * W);
                v = *(const float4*)(src + (size_t)y * W + 4 * c4);
            }
            if (RELU_IN) v = relu4(v);
            *(float4*)&s_in[icl][rr][4 + 4 * c4] = v;
        }
        for (int i = tid; i < ICB * IN_H; i += 256) {
            const int icl = i / IN_H, rr = i - icl * IN_H;
            s_in[icl][rr][3] = 0.0f;
            s_in[icl][rr][W + 4] = 0.0f;
        }
        for (int i = tid; i < ICB * 9 * OCT; i += 256) {
            const int ocl = i % OCT, rest = i / OCT;
            const int k = rest % 9, icl = rest / 9;
            s_w[i] = wgt[((size_t)(oc0 + ocl) * icg + (ic0 + icl)) * 9 + k];
        }
        __syncthreads();

        #pragma unroll 1
        for (int icl = 0; icl < ICB; ++icl) {
            const float* swb = s_w + icl * 9 * OCT + ty * OCB;
            #pragma unroll
            for (int ky = 0; ky < 3; ++ky) {
                #pragma unroll
                for (int kx = 0; kx < 3; ++kx) {
                    const int kq = ky * 3 + kx;
                    float4 wv[NW];
                    #pragma unroll
                    for (int u = 0; u < NW; ++u)
                        wv[u] = *(const float4*)(swb + kq * OCT + 4 * u);
                    #pragma unroll
                    for (int j = 0; j < J; ++j) {
                        const int p = j * 64 + tx;
                        const int rr = p / W, cc = p - rr * W;
                        const float v = s_in[icl][rr + ky][cc + 3 + kx];
                        #pragma unroll
                        for (int u = 0; u < NW; ++u) {
                            acc[4 * u + 0][j] = fmaf(wv[u].x, v, acc[4 * u + 0][j]);
                            acc[4 * u + 1][j] = fmaf(wv[u].y, v, acc[4 * u + 1][j]);
                            acc[4 * u + 2][j] = fmaf(wv[u].z, v, acc[4 * u + 2][j]);
                            acc[4 * u + 3][j] = fmaf(wv[u].w, v, acc[4 * u + 3][j]);
                        }
                    }
                }
            }
        }
    }

    const int HWo = W * W;
    float* ob = out + ((size_t)n * Cout + oc0 + ty * OCB) * HWo;
    #pragma unroll
    for (int o = 0; o < OCB; ++o) {
        #pragma unroll
        for (int j = 0; j < J; ++j) {
            const int p = j * 64 + tx;
            const int rr = p / W, cc = p - rr * W;
            float r = acc[o][j];
            if (relu_out) r = fmaxf(r, 0.0f);
            ob[(size_t)o * HWo + (size_t)(r0 + rr) * W + cc] = r;
        }
    }
}

// ===========================================================================
// 4x4 s2 p1 grouped conv (groups=2). W = OUTPUT width; input 2W x 2W.
// 32 oc x (ROWS*W) px per block; thread: 8 oc x J px.
// ===========================================================================
template<int W, int ROWS>
__global__ __launch_bounds__(256) void conv4s2_kernel(
    const float* __restrict__ in, const float* __restrict__ wgt,
    const float* __restrict__ bias, float* __restrict__ out,
    int Cin, int Cout, int relu_out)
{
    constexpr int J = ROWS * W / 64;
    constexpr int ICB = 4;
    constexpr int IN_H = 2 * ROWS + 2, IN_W2 = 2 * W + 8;
    constexpr int W24 = W / 2;             // float4 per input row
    __shared__ float s_in[ICB][IN_H][IN_W2];
    __shared__ float s_w[ICB * 16 * 32];

    const int tid = threadIdx.x;
    const int tx = tid & 63, ty = tid >> 6;
    const int n = blockIdx.z, oc0 = blockIdx.y * 32, r0 = blockIdx.x * ROWS;
    const int icg = Cin >> 1, ocg = Cout >> 1;
    const int g = oc0 / ocg;
    const int Hin = 2 * W;

    float acc[8][J];
    #pragma unroll
    for (int o = 0; o < 8; ++o) {
        const float b = bias ? bias[oc0 + ty * 8 + o] : 0.0f;
        #pragma unroll
        for (int j = 0; j < J; ++j) acc[o][j] = b;
    }

    const float* inb = in + ((size_t)n * Cin + (size_t)g * icg) * (Hin * Hin);
    for (int ic0 = 0; ic0 < icg; ic0 += ICB) {
        __syncthreads();
        for (int i = tid; i < ICB * IN_H * W24; i += 256) {
            const int icl = i / (IN_H * W24);
            const int rem = i - icl * (IN_H * W24);
            const int rr = rem / W24, c4 = rem - rr * W24;
            const int y = 2 * r0 - 1 + rr;
            float4 v = make_float4(0.f, 0.f, 0.f, 0.f);
            if ((unsigned)y < (unsigned)Hin)
                v = *(const float4*)(inb + (size_t)(ic0 + icl) * (Hin * Hin)
                                     + (size_t)y * Hin + 4 * c4);
            *(float4*)&s_in[icl][rr][4 + 4 * c4] = v;
        }
        for (int i = tid; i < ICB * IN_H; i += 256) {
            const int icl = i / IN_H, rr = i - icl * IN_H;
            s_in[icl][rr][3] = 0.0f;
            s_in[icl][rr][2 * W + 4] = 0.0f;
        }
        for (int i = tid; i < ICB * 16 * 32; i += 256) {
            const int ocl = i & 31, rest = i >> 5;
            const int k = rest & 15, icl = rest >> 4;
            s_w[i] = wgt[((size_t)(oc0 + ocl) * icg + (ic0 + icl)) * 16 + k];
        }
        __syncthreads();

        #pragma unroll 1
        for (int icl = 0; icl < ICB; ++icl) {
            const float* swb = s_w + icl * 512 + ty * 8;
            #pragma unroll
            for (int ky = 0; ky < 4; ++ky) {
                #pragma unroll
                for (int kx = 0; kx < 4; ++kx) {
                    const int kq = ky * 4 + kx;
                    const float4 wA = *(const float4*)(swb + kq * 32);
                    const float4 wB = *(const float4*)(swb + kq * 32 + 4);
                    #pragma unroll
                    for (int j = 0; j < J; ++j) {
                        const int p = j * 64 + tx;
                        const int rr = p / W, cc = p - rr * W;
                        const float v = s_in[icl][2 * rr + ky][2 * cc + 3 + kx];
                        acc[0][j] = fmaf(wA.x, v, acc[0][j]);
                        acc[1][j] = fmaf(wA.y, v, acc[1][j]);
                        acc[2][j] = fmaf(wA.z, v, acc[2][j]);
                        acc[3][j] = fmaf(wA.w, v, acc[3][j]);
                        acc[4][j] = fmaf(wB.x, v, acc[4][j]);
                        acc[5][j] = fmaf(wB.y, v, acc[5][j]);
                        acc[6][j] = fmaf(wB.z, v, acc[6][j]);
                        acc[7][j] = fmaf(wB.w, v, acc[7][j]);
                    }
                }
            }
        }
    }

    const int HWo = W * W;
    float* ob = out + ((size_t)n * Cout + oc0 + ty * 8) * HWo;
    #pragma unroll
    for (int o = 0; o < 8; ++o) {
        #pragma unroll
        for (int j = 0; j < J; ++j) {
            const int p = j * 64 + tx;
            const int rr = p / W, cc = p - rr * W;
            float r = acc[o][j];
            if (relu_out) r = fmaxf(r, 0.0f);
            ob[(size_t)o * HWo + (size_t)(r0 + rr) * W + cc] = r;
        }
    }
}

// ===========================================================================
// 1x1 grouped conv (pixel GEMM). Tile: 32 oc x PX px; thread: 8 oc x PX/64 px.
// ===========================================================================
template<int PX, bool RELU_IN, bool ACC, bool RELU_OUT, bool SPLIT>
__global__ __launch_bounds__(256) void conv1_kernel(
    const float* __restrict__ in, const float* __restrict__ in2,
    const float* __restrict__ wgt, const float* __restrict__ bias,
    float* __restrict__ out, int Cin, int Cout, int HW)
{
    constexpr int J = PX / 64;
    constexpr int PX4 = PX / 4;
    constexpr int ICB = 16;
    __shared__ float s_in[ICB][PX];
    __shared__ float s_w[ICB * 32];

    const int tid = threadIdx.x;
    const int tx = tid & 63, ty = tid >> 6;
    const int n = blockIdx.z, oc0 = blockIdx.y * 32, p0 = blockIdx.x * PX;
    const int icg = Cin >> 1, ocg = Cout >> 1;
    const int g = oc0 / ocg;

    float acc[8][J];
    #pragma unroll
    for (int o = 0; o < 8; ++o) {
        const float b = bias ? bias[oc0 + ty * 8 + o] : 0.0f;
        #pragma unroll
        for (int j = 0; j < J; ++j) acc[o][j] = b;
    }

    const float* inb = SPLIT ? nullptr
                             : in + ((size_t)n * Cin + (size_t)g * icg) * HW + p0;
    for (int ic0 = 0; ic0 < icg; ic0 += ICB) {
        __syncthreads();
        for (int i = tid; i < ICB * PX4; i += 256) {
            const int icl = i / PX4, c4 = i - (i / PX4) * PX4;
            const float* src = SPLIT ? pick_src(in, in2, n, g, ic0 + icl, HW) + p0
                                     : inb + (size_t)(ic0 + icl) * HW;
            float4 v = *(const float4*)(src + 4 * c4);
            if (RELU_IN) v = relu4(v);
            *(float4*)&s_in[icl][4 * c4] = v;
        }
        for (int i = tid; i < ICB * 32; i += 256) {
            const int ocl = i & 31, icl = i >> 5;
            s_w[i] = wgt[(size_t)(oc0 + ocl) * icg + ic0 + icl];
        }
        __syncthreads();

        #pragma unroll 4
        for (int icl = 0; icl < ICB; ++icl) {
            const float4 wA = *(const float4*)(s_w + icl * 32 + ty * 8);
            const float4 wB = *(const float4*)(s_w + icl * 32 + ty * 8 + 4);
            #pragma unroll
            for (int j = 0; j < J; ++j) {
                const float v = s_in[icl][j * 64 + tx];
                acc[0][j] = fmaf(wA.x, v, acc[0][j]);
                acc[1][j] = fmaf(wA.y, v, acc[1][j]);
                acc[2][j] = fmaf(wA.z, v, acc[2][j]);
                acc[3][j] = fmaf(wA.w, v, acc[3][j]);
                acc[4][j] = fmaf(wB.x, v, acc[4][j]);
                acc[5][j] = fmaf(wB.y, v, acc[5][j]);
                acc[6][j] = fmaf(wB.z, v, acc[6][j]);
                acc[7][j] = fmaf(wB.w, v, acc[7][j]);
            }
        }
    }

    float* ob = out + ((size_t)n * Cout + oc0 + ty * 8) * HW + p0;
    #pragma unroll
    for (int o = 0; o < 8; ++o) {
        #pragma unroll
        for (int j = 0; j < J; ++j) {
            const size_t idx = (size_t)o * HW + j * 64 + tx;
            float r = acc[o][j];
            if (ACC) r += ob[idx];
            if (RELU_OUT) r = fmaxf(r, 0.0f);
            ob[idx] = r;
        }
    }
}

// ===========================================================================
// Grouped ConvTranspose2d K4 s2 p1 (groups=2). W = OUTPUT width; input W/2.
// torch layout w: (Cin, Cout/groups, 4, 4). Parity-decomposed taps.
// ===========================================================================
template<int W, int ROWS, int OCT>
__global__ __launch_bounds__(64 * (OCT / 8)) void convt4_kernel(
    const float* __restrict__ in, const float* __restrict__ wgt,
    const float* __restrict__ bias, float* __restrict__ out,
    int Cin, int Cout, int relu_out)
{
    constexpr int NTHR = 64 * (OCT / 8);
    constexpr int PXT  = ROWS * W / 64;
    constexpr int WP   = W / 64;
    constexpr int ICB  = 8;
    constexpr int RIN  = ((ROWS + 1) >> 1) + 2;
    constexpr int CIN  = W / 2 + 2;
    __shared__ float s_in[ICB][RIN][CIN];
    __shared__ float s_w[ICB * 16 * OCT];

    const int tid = threadIdx.x;
    const int tx = tid & 63, ty = tid >> 6;
    const int n = blockIdx.z;
    const int oc0 = blockIdx.y * OCT;
    const int r0 = blockIdx.x * ROWS;       // even
    const int icg = Cin >> 1, ocg = Cout >> 1;
    const int g = oc0 / ocg, of0 = oc0 - g * ocg;
    const int Hin = W / 2;
    const int iy_lo = (r0 - 2) >> 1;

    float acc[8][PXT];
    #pragma unroll
    for (int o = 0; o < 8; ++o) {
        const float b = bias ? bias[oc0 + ty * 8 + o] : 0.0f;
        #pragma unroll
        for (int j = 0; j < PXT; ++j) acc[o][j] = b;
    }

    const float* inb = in + ((size_t)n * Cin + (size_t)g * icg) * (Hin * Hin);
    const int kxl = ((tx + 1) & 1);
    const int hx  = (tx + 1) >> 1;

    for (int ic0 = 0; ic0 < icg; ic0 += ICB) {
        __syncthreads();
        for (int i = tid; i < ICB * RIN * CIN; i += NTHR) {
            const int icl = i / (RIN * CIN);
            const int rem = i - icl * (RIN * CIN);
            const int rr = rem / CIN, cc = rem - rr * CIN;
            const int y = iy_lo + rr, x = cc - 1;
            float v = 0.0f;
            if ((unsigned)y < (unsigned)Hin && (unsigned)x < (unsigned)Hin)
                v = inb[(size_t)(ic0 + icl) * (Hin * Hin) + y * Hin + x];
            s_in[icl][rr][cc] = v;
        }
        for (int i = tid; i < ICB * 16 * OCT; i += NTHR) {
            const int ocl = i & (OCT - 1);
            const int rest = i / OCT;
            const int k = rest & 15, icl = rest >> 4;
            s_w[i] = wgt[((size_t)(g * icg + ic0 + icl) * ocg + of0 + ocl) * 16 + k];
        }
        __syncthreads();

        #pragma unroll 1
        for (int icl = 0; icl < ICB; ++icl) {
            const float* swb = s_w + icl * 16 * OCT + ty * 8;
            #pragma unroll
            for (int tt = 0; tt < 4; ++tt) {
                const int ty2 = tt >> 1, tx2 = tt & 1;
                float4 wp0[2], wp1[2];
                #pragma unroll
                for (int par = 0; par < 2; ++par) {
                    const int koff = ((2 * ty2 + par) * 4 + (kxl + 2 * tx2)) * OCT;
                    wp0[par] = *(const float4*)(swb + koff);
                    wp1[par] = *(const float4*)(swb + koff + 4);
                }
                const int cbase = hx - tx2 + 1;
                #pragma unroll
                for (int j = 0; j < PXT; ++j) {
                    const int row_j = j / WP, m_j = j - row_j * WP;
                    const int pj = (row_j + 1) & 1;
                    const int rloc = (row_j + 1 - pj) / 2 - ty2 + 1;
                    const float v = s_in[icl][rloc][32 * m_j + cbase];
                    const float4 wa = pj ? wp0[1] : wp0[0];
                    const float4 wb = pj ? wp1[1] : wp1[0];
                    acc[0][j] = fmaf(wa.x, v, acc[0][j]);
                    acc[1][j] = fmaf(wa.y, v, acc[1][j]);
                    acc[2][j] = fmaf(wa.z, v, acc[2][j]);
                    acc[3][j] = fmaf(wa.w, v, acc[3][j]);
                    acc[4][j] = fmaf(wb.x, v, acc[4][j]);
                    acc[5][j] = fmaf(wb.y, v, acc[5][j]);
                    acc[6][j] = fmaf(wb.z, v, acc[6][j]);
                    acc[7][j] = fmaf(wb.w, v, acc[7][j]);
                }
            }
        }
    }

    const int HWo = W * W;
    float* ob = out + ((size_t)n * Cout + oc0 + ty * 8) * HWo;
    #pragma unroll
    for (int o = 0; o < 8; ++o) {
        #pragma unroll
        for (int j = 0; j < PXT; ++j) {
            const int row_j = j / WP, m_j = j - row_j * WP;
            float r = acc[o][j];
            if (relu_out) r = fmaxf(r, 0.0f);
            ob[(size_t)o * HWo + (size_t)(r0 + row_j) * W + 64 * m_j + tx] = r;
        }
    }
}

// ===========================================================================
// Fused encoder head (float4): relu(concat(1x1 depth, 1x1 rgb))
// ===========================================================================
__global__ void head_kernel(const float* __restrict__ x,
                            const float* __restrict__ dw, const float* __restrict__ db,
                            const float* __restrict__ rw, const float* __restrict__ rb,
                            float* __restrict__ out)
{
    const int idx = blockIdx.x * TPB + threadIdx.x;       // f4 index
    const int HW4 = 16384;
    if (idx >= 8 * 64 * HW4) return;
    const int p4 = idx & (HW4 - 1);
    const int t = idx >> 14;
    const int c = t & 63, n = t >> 6;
    const float4* xb4 = (const float4*)(x + (size_t)n * 4 * 65536);
    float4 v;
    if (c < 32) {
        const float w = dw[c], b = db[c];
        const float4 d = xb4[p4];
        v.x = fmaf(d.x, w, b); v.y = fmaf(d.y, w, b);
        v.z = fmaf(d.z, w, b); v.w = fmaf(d.w, w, b);
    } else {
        const int cc = c - 32;
        const float w0 = rw[cc * 3], w1 = rw[cc * 3 + 1], w2 = rw[cc * 3 + 2];
        const float b = rb[cc];
        const float4 r = xb4[HW4 + p4], g4 = xb4[2 * HW4 + p4], bl = xb4[3 * HW4 + p4];
        v.x = fmaf(bl.x, w2, fmaf(g4.x, w1, fmaf(r.x, w0, b)));
        v.y = fmaf(bl.y, w2, fmaf(g4.y, w1, fmaf(r.y, w0, b)));
        v.z = fmaf(bl.z, w2, fmaf(g4.z, w1, fmaf(r.z, w0, b)));
        v.w = fmaf(bl.w, w2, fmaf(g4.w, w1, fmaf(r.w, w0, b)));
    }
    ((float4*)out)[idx] = relu4(v);
}

// Precompute |emb_k|^2
__global__ void emb_norm_kernel(const float* __restrict__ emb, float* __restrict__ en, int K)
{
    const int k = blockIdx.x * TPB + threadIdx.x;
    if (k >= K) return;
    const float4* e = (const float4*)(emb + (size_t)k * 128);
    float s = 0.0f;
    for (int c = 0; c < 32; ++c) {
        const float4 t = e[c];
        s = fmaf(t.x, t.x, s); s = fmaf(t.y, t.y, s);
        s = fmaf(t.z, t.z, s); s = fmaf(t.w, t.w, s);
    }
    en[k] = s;
}

// ===========================================================================
// VQ: 64 z-vectors per block; register tile 4v x 4e; float4 c-chunks in LDS.
// ===========================================================================
#define VQ_TV 64
#define VQ_TE 64
__global__ __launch_bounds__(256) void vq_kernel(
    const float* __restrict__ z, const float* __restrict__ emb,
    const float* __restrict__ en_g,
    float* __restrict__ q, float* __restrict__ lossp,
    int HW, int Kc)
{
    __shared__ float zs[32][65][4];
    __shared__ float es[32][65][4];
    __shared__ float en[VQ_TE];
    __shared__ float rdd[VQ_TV][16];
    __shared__ int   rdi[VQ_TV][16];
    __shared__ int   idxv[VQ_TV];
    __shared__ float red[256];

    const int tid = threadIdx.x;
    const int vg = tid >> 4, eg = tid & 15;
    const long long gv0 = (long long)blockIdx.x * VQ_TV;
    const int n = (int)(gv0 / HW);
    const int p0 = (int)(gv0 - (long long)n * HW);
    const float* zb = z + (size_t)n * 128 * HW + p0;

    for (int i = tid; i < 64 * 128; i += 256) {
        const int v = i & 63, c = i >> 6;
        zs[c >> 2][v][c & 3] = zb[(size_t)c * HW + v];
    }
    __syncthreads();

    float best[4]; int bidx[4];
    #pragma unroll
    for (int r = 0; r < 4; ++r) { best[r] = 1e30f; bidx[r] = 0; }

    for (int e0 = 0; e0 < Kc; e0 += VQ_TE) {
        for (int i = tid; i < VQ_TE * 128; i += 256) {
            const int c = i & 127, el = i >> 7;
            es[c >> 2][el][c & 3] = emb[(size_t)(e0 + el) * 128 + c];
        }
        if (tid < VQ_TE) en[tid] = en_g[e0 + tid];
        __syncthreads();

        float dot[4][4];
        #pragma unroll
        for (int r = 0; r < 4; ++r)
            #pragma unroll
            for (int s = 0; s < 4; ++s) dot[r][s] = 0.0f;

        for (int c4 = 0; c4 < 32; ++c4) {
            float4 zr[4], ee[4];
            #pragma unroll
            for (int r = 0; r < 4; ++r) zr[r] = *(const float4*)&zs[c4][4 * vg + r][0];
            #pragma unroll
            for (int s = 0; s < 4; ++s) ee[s] = *(const float4*)&es[c4][eg + 16 * s][0];
            #pragma unroll
            for (int r = 0; r < 4; ++r) {
                #pragma unroll
                for (int s = 0; s < 4; ++s) {
                    dot[r][s] = fmaf(zr[r].x, ee[s].x, dot[r][s]);
                    dot[r][s] = fmaf(zr[r].y, ee[s].y, dot[r][s]);
                    dot[r][s] = fmaf(zr[r].z, ee[s].z, dot[r][s]);
                    dot[r][s] = fmaf(zr[r].w, ee[s].w, dot[r][s]);
                }
            }
        }
        #pragma unroll
        for (int s = 0; s < 4; ++s) {
            const float e2 = en[eg + 16 * s];
            const int ei = e0 + eg + 16 * s;
            #pragma unroll
            for (int r = 0; r < 4; ++r) {
                const float d = e2 - 2.0f * dot[r][s];
                if (d < best[r]) { best[r] = d; bidx[r] = ei; }
            }
        }
        __syncthreads();
    }

    #pragma unroll
    for (int r = 0; r < 4; ++r) { rdd[4 * vg + r][eg] = best[r]; rdi[4 * vg + r][eg] = bidx[r]; }
    __syncthreads();
    if (tid < VQ_TV) {
        float bd = rdd[tid][0]; int bi = rdi[tid][0];
        for (int j = 1; j < 16; ++j) {
            const float d = rdd[tid][j]; const int i2 = rdi[tid][j];
            if (d < bd || (d == bd && i2 < bi)) { bd = d; bi = i2; }
        }
        idxv[tid] = bi;
    }
    __syncthreads();

    float ls = 0.0f;
    float* qb = q + (size_t)n * 128 * HW + p0;
    for (int i = tid; i < 64 * 128; i += 256) {
        const int v = i & 63, c = i >> 6;
        const float e = emb[(size_t)idxv[v] * 128 + c];
        qb[(size_t)c * HW + v] = e;
        const float diff = e - zs[c >> 2][v][c & 3];
        ls = fmaf(diff, diff, ls);
    }
    red[tid] = ls;
    __syncthreads();
    for (int s = 128; s > 0; s >>= 1) {
        if (tid < s) red[tid] += red[tid + s];
        __syncthreads();
    }
    if (tid == 0) lossp[blockIdx.x] = red[0];
}

__global__ void loss_finish_kernel(const float* __restrict__ p, int n, float scale,
                                   float* __restrict__ out)
{
    __shared__ float red[256];
    float s = 0.0f;
    for (int i = threadIdx.x; i < n; i += 256) s += p[i];
    red[threadIdx.x] = s;
    __syncthreads();
    for (int k = 128; k > 0; k >>= 1) {
        if (threadIdx.x < k) red[threadIdx.x] += red[threadIdx.x + k];
        __syncthreads();
    }
    if (threadIdx.x == 0) out[0] = red[0] * scale;
}

// Final 1x1 heads (float4): y2 (8,32,256,256) -> recon (8,4,256,256)
__global__ void outconv_kernel(const float* __restrict__ y,
                               const float* __restrict__ odw, const float* __restrict__ odb,
                               const float* __restrict__ orw, const float* __restrict__ orb,
                               float* __restrict__ out)
{
    const int idx = blockIdx.x * TPB + threadIdx.x;      // f4 index
    const int HW4 = 16384;
    if (idx >= 8 * 4 * HW4) return;
    const int p4 = idx & (HW4 - 1);
    const int t = idx >> 14;
    const int c = t & 3, n = t >> 2;
    const float4* yb4 = (const float4*)(y + (size_t)n * 32 * 65536);
    float4 v;
    const int base = (c == 0) ? 0 : 16;
    const float* wv = (c == 0) ? odw : orw + (c - 1) * 16;
    const float b = (c == 0) ? odb[0] : orb[c - 1];
    v.x = b; v.y = b; v.z = b; v.w = b;
    for (int k = 0; k < 16; ++k) {
        const float w = wv[k];
        const float4 f = yb4[(size_t)(base + k) * HW4 + p4];
        v.x = fmaf(f.x, w, v.x); v.y = fmaf(f.y, w, v.y);
        v.z = fmaf(f.z, w, v.z); v.w = fmaf(f.w, w, v.w);
    }
    ((float4*)out)[idx] = v;
}

extern "C" void kernel_launch(void* const* d_in, const int* in_sizes, int n_in,
                              void* d_out, int out_size, void* d_ws, size_t ws_size,
                              hipStream_t stream)
{
    const float* x      = (const float*)d_in[0];
    const float* eb_dw  = (const float*)d_in[1];
    const float* eb_db  = (const float*)d_in[2];
    const float* eb_rw  = (const float*)d_in[3];
    const float* eb_rb  = (const float*)d_in[4];
    const float* eb_c1w = (const float*)d_in[5];
    const float* eb_c1b = (const float*)d_in[6];
    const float* eb_c2w = (const float*)d_in[7];
    const float* eb_c2b = (const float*)d_in[8];
    const float* eb_c3w = (const float*)d_in[9];
    const float* eb_c3b = (const float*)d_in[10];
    const float* eb_rw1 = (const float*)d_in[11];
    const float* eb_rw2 = (const float*)d_in[12];
    const float* et_c1w = (const float*)d_in[13];
    const float* et_c1b = (const float*)d_in[14];
    const float* et_c2w = (const float*)d_in[15];
    const float* et_c2b = (const float*)d_in[16];
    const float* et_rw1 = (const float*)d_in[17];
    const float* et_rw2 = (const float*)d_in[18];
    const float* pvt_w  = (const float*)d_in[19];
    const float* pvt_b  = (const float*)d_in[20];
    const float* up_w   = (const float*)d_in[21];
    const float* up_b   = (const float*)d_in[22];
    const float* pvb_w  = (const float*)d_in[23];
    const float* pvb_b  = (const float*)d_in[24];
    const float* emb_t  = (const float*)d_in[25];
    const float* emb_b  = (const float*)d_in[26];
    const float* db_c1w = (const float*)d_in[27];
    const float* db_c1b = (const float*)d_in[28];
    const float* db_rw1 = (const float*)d_in[29];
    const float* db_rw2 = (const float*)d_in[30];
    const float* db_t1w = (const float*)d_in[31];
    const float* db_t1b = (const float*)d_in[32];
    const float* db_t2w = (const float*)d_in[33];
    const float* db_t2b = (const float*)d_in[34];
    const float* db_odw = (const float*)d_in[35];
    const float* db_odb = (const float*)d_in[36];
    const float* db_orw = (const float*)d_in[37];
    const float* db_orb = (const float*)d_in[38];

    float* ws  = (float*)d_ws;
    float* out = (float*)d_out;

    // ---- workspace arena (float offsets). Verified disjoint live ranges
    //      (see round-4 proof; unchanged this round).
    const size_t OFF_H0   = 0;
    const size_t OFF_H1   = 33554432;
    const size_t OFF_H2   = 0;
    const size_t OFF_ENCB = 4194304;
    const size_t OFF_RH   = 8388608;
    const size_t OFF_T1   = 10485760;
    const size_t OFF_T2   = 11534336;
    const size_t OFF_ZT   = 12582912;
    const size_t OFF_UPT  = 13631488;
    const size_t OFF_ZB   = 17825792;
    const size_t OFF_Y    = 22020096;
    const size_t OFF_Y1   = 26214400;
    const size_t OFF_Y2   = 0;
    const size_t OFF_ENT  = 34603008;
    const size_t OFF_ENB  = 34605056;
    const size_t OFF_LPT  = 34607104;
    const size_t OFF_LPB  = 34607232;
    const size_t NEED     = 41943680;
    if (ws_size < NEED * sizeof(float)) return;

    // ---- output layout: loss_b, loss_t, recon, q_t, q_b ----
    float* o_loss_b = out + 0;
    float* o_loss_t = out + 1;
    float* o_recon  = out + 2;
    float* o_qt     = out + 2 + 8 * 4 * 65536;
    float* o_qb     = o_qt + 8 * 128 * 1024;

    // ===== EncoderBot =====
    head_kernel<<<8 * 64 * 16384 / TPB, TPB, 0, stream>>>(
        x, eb_dw, eb_db, eb_rw, eb_rb, ws + OFF_H0);
    conv4s2_kernel<128, 2><<<dim3(64, 2, 8), 256, 0, stream>>>(
        ws + OFF_H0, eb_c1w, eb_c1b, ws + OFF_H1, 64, 64, 1);
    conv4s2_kernel<64, 4><<<dim3(16, 4, 8), 256, 0, stream>>>(
        ws + OFF_H1, eb_c2w, eb_c2b, ws + OFF_H2, 64, 128, 1);
    emb_norm_kernel<<<8, TPB, 0, stream>>>(emb_t, ws + OFF_ENT, 2048);
    emb_norm_kernel<<<8, TPB, 0, stream>>>(emb_b, ws + OFF_ENB, 2048);
    conv3_kernel<64, 4, 8, false, false><<<dim3(16, 4, 8), 256, 0, stream>>>(
        ws + OFF_H2, nullptr, eb_c3w, eb_c3b, ws + OFF_ENCB, 128, 128, 0);
    for (int i = 0; i < 2; ++i) {
        conv3_kernel<64, 4, 4, true, false><<<dim3(16, 4, 8), 256, 0, stream>>>(
            ws + OFF_ENCB, nullptr, eb_rw1 + (size_t)i * 64 * 64 * 9, nullptr,
            ws + OFF_RH, 128, 64, 0);
        if (i == 1)
            conv1_kernel<256, true, true, true, false><<<dim3(16, 4, 8), 256, 0, stream>>>(
                ws + OFF_RH, nullptr, eb_rw2 + (size_t)i * 128 * 32, nullptr,
                ws + OFF_ENCB, 64, 128, 4096);
        else
            conv1_kernel<256, true, true, false, false><<<dim3(16, 4, 8), 256, 0, stream>>>(
                ws + OFF_RH, nullptr, eb_rw2 + (size_t)i * 128 * 32, nullptr,
                ws + OFF_ENCB, 64, 128, 4096);
    }

    // ===== EncoderTop =====
    conv4s2_kernel<32, 4><<<dim3(8, 4, 8), 256, 0, stream>>>(
        ws + OFF_ENCB, et_c1w, et_c1b, ws + OFF_T1, 128, 128, 1);
    conv3_kernel<32, 4, 8, false, false><<<dim3(8, 4, 8), 256, 0, stream>>>(
        ws + OFF_T1, nullptr, et_c2w, et_c2b, ws + OFF_T2, 128, 128, 1);
    for (int i = 0; i < 2; ++i) {
        conv3_kernel<32, 4, 4, true, false><<<dim3(8, 4, 8), 256, 0, stream>>>(
            ws + OFF_T2, nullptr, et_rw1 + (size_t)i * 64 * 64 * 9, nullptr,
            ws + OFF_RH, 128, 64, 0);
        if (i == 1)
            conv1_kernel<128, true, true, true, false><<<dim3(8, 4, 8), 256, 0, stream>>>(
                ws + OFF_RH, nullptr, et_rw2 + (size_t)i * 128 * 32, nullptr,
                ws + OFF_T2, 64, 128, 1024);
        else
            conv1_kernel<128, true, true, false, false><<<dim3(8, 4, 8), 256, 0, stream>>>(
                ws + OFF_RH, nullptr, et_rw2 + (size_t)i * 128 * 32, nullptr,
                ws + OFF_T2, 64, 128, 1024);
    }

    // ===== top VQ =====
    conv1_kernel<128, false, false, false, false><<<dim3(8, 4, 8), 256, 0, stream>>>(
        ws + OFF_T2, nullptr, pvt_w, pvt_b, ws + OFF_ZT, 128, 128, 1024);
    vq_kernel<<<128, 256, 0, stream>>>(ws + OFF_ZT, emb_t, ws + OFF_ENT, o_qt,
                                       ws + OFF_LPT, 1024, 2048);
    loss_finish_kernel<<<1, 256, 0, stream>>>(ws + OFF_LPT, 128,
                                              0.25f / (8192.0f * 128.0f), o_loss_t);

    convt4_kernel<64, 4, 32><<<dim3(16, 4, 8), 256, 0, stream>>>(
        o_qt, up_w, up_b, ws + OFF_UPT, 128, 128, 0);

    // ===== PreVQBot / bottom VQ (regroup fused into conv1 staging) =====
    conv1_kernel<256, false, false, false, true><<<dim3(16, 4, 8), 256, 0, stream>>>(
        ws + OFF_ENCB, ws + OFF_UPT, pvb_w, pvb_b, ws + OFF_ZB, 256, 128, 4096);
    vq_kernel<<<512, 256, 0, stream>>>(ws + OFF_ZB, emb_b, ws + OFF_ENB, o_qb,
                                       ws + OFF_LPB, 4096, 2048);
    loss_finish_kernel<<<1, 256, 0, stream>>>(ws + OFF_LPB, 512,
                                              0.25f / (32768.0f * 128.0f), o_loss_b);

    // ===== DecoderBot (regroup fused into conv3 staging) =====
    conv3_kernel<64, 4, 8, false, true><<<dim3(16, 4, 8), 256, 0, stream>>>(
        ws + OFF_UPT, o_qb, db_c1w, db_c1b, ws + OFF_Y, 256, 128, 0);
    for (int i = 0; i < 2; ++i) {
        conv3_kernel<64, 4, 4, true, false><<<dim3(16, 4, 8), 256, 0, stream>>>(
            ws + OFF_Y, nullptr, db_rw1 + (size_t)i * 64 * 64 * 9, nullptr,
            ws + OFF_RH, 128, 64, 0);
        if (i == 1)
            conv1_kernel<256, true, true, true, false><<<dim3(16, 4, 8), 256, 0, stream>>>(
                ws + OFF_RH, nullptr, db_rw2 + (size_t)i * 128 * 32, nullptr,
                ws + OFF_Y, 64, 128, 4096);
        else
            conv1_kernel<256, true, true, false, false><<<dim3(16, 4, 8), 256, 0, stream>>>(
                ws + OFF_RH, nullptr, db_rw2 + (size_t)i * 128 * 32, nullptr,
                ws + OFF_Y, 64, 128, 4096);
    }
    convt4_kernel<128, 2, 32><<<dim3(64, 2, 8), 256, 0, stream>>>(
        ws + OFF_Y, db_t1w, db_t1b, ws + OFF_Y1, 128, 64, 1);
    convt4_kernel<256, 2, 16><<<dim3(128, 2, 8), 128, 0, stream>>>(
        ws + OFF_Y1, db_t2w, db_t2b, ws + OFF_Y2, 64, 32, 0);
    outconv_kernel<<<8 * 4 * 16384 / TPB, TPB, 0, stream>>>(
        ws + OFF_Y2, db_odw, db_odb, db_orw, db_orb, o_recon);
}